// Round 2
// baseline (3194.135 us; speedup 1.0000x reference)
//
#include <hip/hip_runtime.h>
#include <hip/hip_bf16.h>

// Problem constants (MoR Llama decoder layer)
#define B_  2
#define S_  1024
#define D_  2048
#define H_  16
#define HD_ 128
#define FF_ 8192
#define R_  3
#define T_  (B_*S_)

typedef __attribute__((ext_vector_type(8))) short bf16x8;   // 8 x bf16 (4 VGPR) MFMA frag
typedef __attribute__((ext_vector_type(4))) float f32x4;    // MFMA accumulator
using bf16 = __hip_bfloat16;

// ---------- helpers ----------
__device__ __forceinline__ float bf2f(short s) {
    return __uint_as_float(((unsigned)(unsigned short)s) << 16);
}
__device__ __forceinline__ unsigned f2bf_bits(float f) {
    bf16 h = __float2bfloat16(f);
    unsigned short u; __builtin_memcpy(&u, &h, 2);
    return (unsigned)u;
}
__device__ __forceinline__ unsigned pack2(float a, float b) {
    return f2bf_bits(a) | (f2bf_bits(b) << 16);
}
__device__ __forceinline__ float wsum(float v) {
    #pragma unroll
    for (int m = 32; m; m >>= 1) v += __shfl_xor(v, m);
    return v;
}
__device__ __forceinline__ float wmax(float v) {
    #pragma unroll
    for (int m = 32; m; m >>= 1) v = fmaxf(v, __shfl_xor(v, m));
    return v;
}
__device__ __forceinline__ void load_lds16(const void* g, void* l) {
    // async global->LDS, 16B per lane; LDS dest is wave-uniform base + lane*16
    __builtin_amdgcn_global_load_lds((const __attribute__((address_space(1))) void*)g,
                                     (__attribute__((address_space(3))) void*)l, 16, 0, 0);
}

// ---------- weight transpose+cast: W[K][N] f32 -> Wt[N][K] bf16 ----------
__global__ __launch_bounds__(256)
void transpose_cast(const float* __restrict__ W, bf16* __restrict__ Wt, int K, int N) {
    __shared__ float tile[32][33];
    const int n0 = blockIdx.x * 32, k0 = blockIdx.y * 32;
    const int c = threadIdx.x & 31, r8 = threadIdx.x >> 5;
    #pragma unroll
    for (int i = 0; i < 4; i++) {
        int r = r8 + i * 8;
        tile[r][c] = W[(long)(k0 + r) * N + n0 + c];
    }
    __syncthreads();
    #pragma unroll
    for (int i = 0; i < 4; i++) {
        int r = r8 + i * 8;
        Wt[(long)(n0 + r) * K + k0 + c] = __float2bfloat16(tile[c][r]);
    }
}

// ---------- router: probs=softmax(x@Wr), top=argmax, w=probs[top] ----------
__global__ __launch_bounds__(256)
void router_k(const float* __restrict__ X, const float* __restrict__ Wr,
              int* __restrict__ top, float* __restrict__ wsel) {
    const int t = blockIdx.x * 4 + (threadIdx.x >> 6);
    const int lane = threadIdx.x & 63;
    const float* x = X + (long)t * D_;
    float a0 = 0.f, a1 = 0.f, a2 = 0.f;
    for (int j = lane; j < D_; j += 64) {
        float xv = x[j];
        a0 += xv * Wr[j * 3 + 0];
        a1 += xv * Wr[j * 3 + 1];
        a2 += xv * Wr[j * 3 + 2];
    }
    a0 = wsum(a0); a1 = wsum(a1); a2 = wsum(a2);
    if (lane == 0) {
        int arg = 0; float bm = a0;
        if (a1 > bm) { bm = a1; arg = 1; }
        if (a2 > bm) { bm = a2; arg = 2; }
        float s = expf(a0 - bm) + expf(a1 - bm) + expf(a2 - bm);
        top[t]  = arg;
        wsel[t] = 1.0f / s;   // softmax value at argmax (TEMP=ALPHA=1)
    }
}

// ---------- RMSNorm f32 -> bf16 (one block per token) ----------
__global__ __launch_bounds__(256)
void rmsnorm_k(const float* __restrict__ X, const float* __restrict__ G, bf16* __restrict__ Hb) {
    const int t = blockIdx.x, tid = threadIdx.x;
    const float4* xr = (const float4*)(X + (long)t * D_);
    float4 v0 = xr[tid], v1 = xr[tid + 256];
    float ss = v0.x*v0.x + v0.y*v0.y + v0.z*v0.z + v0.w*v0.w
             + v1.x*v1.x + v1.y*v1.y + v1.z*v1.z + v1.w*v1.w;
    ss = wsum(ss);
    __shared__ float red[4];
    if ((tid & 63) == 0) red[tid >> 6] = ss;
    __syncthreads();
    const float r = rsqrtf((red[0] + red[1] + red[2] + red[3]) * (1.0f / D_) + 1e-6f);
    const float4* gr = (const float4*)G;
    float4 g0 = gr[tid], g1 = gr[tid + 256];
    uint2* ob = (uint2*)(Hb + (long)t * D_);
    uint2 o;
    o.x = pack2(v0.x * r * g0.x, v0.y * r * g0.y);
    o.y = pack2(v0.z * r * g0.z, v0.w * r * g0.w);
    ob[tid] = o;
    o.x = pack2(v1.x * r * g1.x, v1.y * r * g1.y);
    o.y = pack2(v1.z * r * g1.z, v1.w * r * g1.w);
    ob[tid + 256] = o;
}

// ---------- RoPE in-place on q,k (bf16) ----------
__global__ __launch_bounds__(256)
void rope_k(bf16* __restrict__ q, bf16* __restrict__ k,
            const float* __restrict__ cosb, const float* __restrict__ sinb) {
    const int idx = blockIdx.x * 256 + threadIdx.x;   // T*H*64 threads
    const int d = idx & 63;
    const int h = (idx >> 6) & (H_ - 1);
    const int t = idx >> 10;
    const int s = t & (S_ - 1);
    const long base = (long)t * D_ + h * HD_;
    const float c1 = cosb[s * HD_ + d],      s1 = sinb[s * HD_ + d];
    const float c2 = cosb[s * HD_ + d + 64], s2 = sinb[s * HD_ + d + 64];
    float q1 = __bfloat162float(q[base + d]), q2 = __bfloat162float(q[base + d + 64]);
    q[base + d]      = __float2bfloat16(q1 * c1 - q2 * s1);
    q[base + d + 64] = __float2bfloat16(q2 * c2 + q1 * s2);
    float k1 = __bfloat162float(k[base + d]), k2 = __bfloat162float(k[base + d + 64]);
    k[base + d]      = __float2bfloat16(k1 * c1 - k2 * s1);
    k[base + d + 64] = __float2bfloat16(k2 * c2 + k1 * s2);
}

// ---------- flash attention (online softmax, causal + sel mask) ----------
// grid (S/16, H, B); block 256 = 4 waves; wave w owns 4 queries; lane = key.
__global__ __launch_bounds__(256)
void attn_k(const bf16* __restrict__ qb, const bf16* __restrict__ kb, const bf16* __restrict__ vb,
            const int* __restrict__ top, int rec, bf16* __restrict__ aob) {
    __shared__ bf16 Ks[64 * 128];   // XOR-swizzled cols (G4 fix for [64][128] 32-way conflict)
    __shared__ bf16 Vs[64 * 128];   // linear
    __shared__ bf16 Qs[16 * 128];
    __shared__ float Ps[16 * 64];
    const int q0 = blockIdx.x * 16;
    const int h = blockIdx.y, b = blockIdx.z;
    const int tid = threadIdx.x, w = tid >> 6, lane = tid & 63;

    { // Q tile
        int r = tid >> 4, c = tid & 15;
        *(uint4*)&Qs[r * 128 + c * 8] =
            *(const uint4*)&qb[((long)((b * S_ + q0 + r) * H_ + h)) * HD_ + c * 8];
    }
    float mrun[4] = {-1e30f, -1e30f, -1e30f, -1e30f};
    float lrun[4] = {0.f, 0.f, 0.f, 0.f};
    float oa[4][2] = {};
    const int nch = (q0 + 15) / 64 + 1;
    for (int kc = 0; kc < nch; kc++) {
        __syncthreads();
        #pragma unroll
        for (int i = 0; i < 4; i++) {   // stage K (swizzled) + V (linear)
            int idx = tid + 256 * i; int r = idx >> 4, c = idx & 15;
            long g = ((long)((b * S_ + kc * 64 + r) * H_ + h)) * HD_;
            *(uint4*)&Ks[r * 128 + c * 8] = *(const uint4*)&kb[g + ((c ^ (r & 7)) * 8)];
            *(uint4*)&Vs[r * 128 + c * 8] = *(const uint4*)&vb[g + c * 8];
        }
        __syncthreads();
        const int key = kc * 64 + lane;
        const bool selb = (top[b * S_ + key] >= rec);
        #pragma unroll
        for (int qi = 0; qi < 4; qi++) {
            const int qq = q0 + w * 4 + qi;
            float s = 0.f;
            #pragma unroll
            for (int c = 0; c < 16; c++) {
                bf16x8 kf = *(const bf16x8*)&Ks[lane * 128 + ((c ^ (lane & 7)) * 8)];
                bf16x8 qf = *(const bf16x8*)&Qs[(w * 4 + qi) * 128 + c * 8];
                #pragma unroll
                for (int e = 0; e < 8; e++) s += bf2f(kf[e]) * bf2f(qf[e]);
            }
            s *= 0.088388347648318447f;   // 1/sqrt(128)
            if (!selb || key > qq) s = -1e9f;
            float smax = wmax(s);
            float mnew = fmaxf(mrun[qi], smax);
            float p = __expf(s - mnew);
            float psum = wsum(p);
            float sc = __expf(mrun[qi] - mnew);
            lrun[qi] = lrun[qi] * sc + psum;
            oa[qi][0] *= sc; oa[qi][1] *= sc;
            mrun[qi] = mnew;
            Ps[(w * 4 + qi) * 64 + lane] = p;
        }
        // PV: lane = d-pair (d = 2*lane, 2*lane+1); Ps reads are wave-local (no barrier needed)
        #pragma unroll 4
        for (int k4 = 0; k4 < 16; k4++) {
            float4 pq[4];
            #pragma unroll
            for (int qi = 0; qi < 4; qi++)
                pq[qi] = *(const float4*)&Ps[(w * 4 + qi) * 64 + k4 * 4];
            #pragma unroll
            for (int j = 0; j < 4; j++) {
                unsigned vv = *(const unsigned*)&Vs[(k4 * 4 + j) * 128 + lane * 2];
                float v0 = __uint_as_float(vv << 16);
                float v1 = __uint_as_float(vv & 0xffff0000u);
                #pragma unroll
                for (int qi = 0; qi < 4; qi++) {
                    float pj = ((const float*)&pq[qi])[j];
                    oa[qi][0] += pj * v0;
                    oa[qi][1] += pj * v1;
                }
            }
        }
    }
    #pragma unroll
    for (int qi = 0; qi < 4; qi++) {
        const int qq = q0 + w * 4 + qi;
        float inv = 1.0f / lrun[qi];
        unsigned o = pack2(oa[qi][0] * inv, oa[qi][1] * inv);
        *(unsigned*)&aob[((long)((b * S_ + qq) * H_ + h)) * HD_ + lane * 2] = o;
    }
}

// ---------- bf16 MFMA GEMM (m97 structure): C = A[M][K] @ Bt[N][K]^T ----------
// EP 0: store bf16  (z-dim selects Bt0..2 / C0..2 for fused QKV)
// EP 1: xout = acc + resid (f32)
// EP 2: taux = bf16(silu(acc) * uaux)   (in-place on u is safe: same thread r/w)
// EP 3: o = acc + resid; if(top==rec) final=o*wsel; if(top>=rec) cur=o
template<int EP>
__global__ __launch_bounds__(256)
void gemm_k(const bf16* __restrict__ A,
            const bf16* __restrict__ Bt0, const bf16* __restrict__ Bt1, const bf16* __restrict__ Bt2,
            bf16* __restrict__ C0, bf16* __restrict__ C1, bf16* __restrict__ C2,
            const float* __restrict__ resid, float* __restrict__ xout,
            const bf16* __restrict__ uaux, bf16* __restrict__ taux,
            const int* __restrict__ topidx, const float* __restrict__ wsel,
            float* __restrict__ finalp, float* __restrict__ curp, int rec,
            int N, int K) {
    __shared__ bf16 As[128 * 32];
    __shared__ bf16 Bs[128 * 32];
    const int tid = threadIdx.x;
    const int w = tid >> 6, lane = tid & 63;
    const int m0 = blockIdx.x * 128, n0 = blockIdx.y * 128;
    const bf16* Bt = (blockIdx.z == 0) ? Bt0 : ((blockIdx.z == 1) ? Bt1 : Bt2);
    bf16* Cb       = (blockIdx.z == 0) ? C0  : ((blockIdx.z == 1) ? C1  : C2);

    const int srow = lane >> 2;          // staging row within 16-row group
    const int scol = (lane & 3) * 8;     // staging k-offset (elements)
    const long gA = (long)(m0 + w * 32 + srow) * K + scol;
    const long gB = (long)(n0 + w * 32 + srow) * K + scol;

    const int wr = w >> 1, wc = w & 1;   // wave tile (64x64)
    const int fm = lane & 15, kg = lane >> 4;

    f32x4 acc[4][4] = {};

    for (int kt = 0; kt < K; kt += 32) {
        __syncthreads();
        #pragma unroll
        for (int i = 0; i < 2; i++) {
            load_lds16(A  + gA + (long)(16 * i) * K + kt, &As[(w * 32 + 16 * i) * 32]);
            load_lds16(Bt + gB + (long)(16 * i) * K + kt, &Bs[(w * 32 + 16 * i) * 32]);
        }
        __syncthreads();
        bf16x8 af[4], bfr[4];
        #pragma unroll
        for (int mi = 0; mi < 4; mi++)
            af[mi] = *(const bf16x8*)&As[(wr * 64 + mi * 16 + fm) * 32 + kg * 8];
        #pragma unroll
        for (int ni = 0; ni < 4; ni++)
            bfr[ni] = *(const bf16x8*)&Bs[(wc * 64 + ni * 16 + fm) * 32 + kg * 8];
        #pragma unroll
        for (int mi = 0; mi < 4; mi++)
            #pragma unroll
            for (int ni = 0; ni < 4; ni++)
                acc[mi][ni] = __builtin_amdgcn_mfma_f32_16x16x32_bf16(af[mi], bfr[ni], acc[mi][ni], 0, 0, 0);
    }
    // epilogue; C/D layout: col = lane&15, row = (lane>>4)*4 + j  [m89-verified]
    #pragma unroll
    for (int mi = 0; mi < 4; mi++) {
        #pragma unroll
        for (int j = 0; j < 4; j++) {
            const int m = m0 + wr * 64 + mi * 16 + kg * 4 + j;
            int   ti = 0; float wv = 0.f;
            if (EP == 3) { ti = topidx[m]; wv = wsel[m]; }
            #pragma unroll
            for (int ni = 0; ni < 4; ni++) {
                const int n = n0 + wc * 64 + ni * 16 + fm;
                const long off = (long)m * N + n;
                float v = acc[mi][ni][j];
                if (EP == 0) {
                    Cb[off] = __float2bfloat16(v);
                } else if (EP == 1) {
                    xout[off] = v + resid[off];
                } else if (EP == 2) {
                    float u = __bfloat162float(uaux[off]);
                    taux[off] = __float2bfloat16(u * v / (1.f + __expf(-v)));
                } else {
                    float o = v + resid[off];
                    if (ti == rec) finalp[off] = o * wv;
                    if (ti >= rec) curp[off] = o;
                }
            }
        }
    }
}

// ---------- host ----------
extern "C" void kernel_launch(void* const* d_in, const int* in_sizes, int n_in,
                              void* d_out, int out_size, void* d_ws, size_t ws_size,
                              hipStream_t stream) {
    const float* x    = (const float*)d_in[0];
    const float* cosb = (const float*)d_in[1];
    const float* sinb = (const float*)d_in[2];
    const float* wrt  = (const float*)d_in[3];
    const float* ln1  = (const float*)d_in[4];
    const float* ln2  = (const float*)d_in[5];
    const float* Wq   = (const float*)d_in[6];
    const float* Wk   = (const float*)d_in[7];
    const float* Wv   = (const float*)d_in[8];
    const float* Wo   = (const float*)d_in[9];
    const float* Wg   = (const float*)d_in[10];
    const float* Wu   = (const float*)d_in[11];
    const float* Wd   = (const float*)d_in[12];

    char* p = (char*)d_ws;
    auto take = [&](size_t bytes) -> char* {
        char* r = p; p += (bytes + 255) & ~(size_t)255; return r;
    };
    // bf16 transposed weights  (~128 MB)
    bf16* WqT = (bf16*)take((size_t)D_ * D_ * 2);
    bf16* WkT = (bf16*)take((size_t)D_ * D_ * 2);
    bf16* WvT = (bf16*)take((size_t)D_ * D_ * 2);
    bf16* WoT = (bf16*)take((size_t)D_ * D_ * 2);
    bf16* WgT = (bf16*)take((size_t)D_ * FF_ * 2);
    bf16* WuT = (bf16*)take((size_t)D_ * FF_ * 2);
    bf16* WdT = (bf16*)take((size_t)D_ * FF_ * 2);
    // activations (~104 MB)
    float* cur  = (float*)take((size_t)T_ * D_ * 4);
    float* xnew = (float*)take((size_t)T_ * D_ * 4);
    bf16*  hb   = (bf16*)take((size_t)T_ * D_ * 2);
    bf16*  qb   = (bf16*)take((size_t)T_ * D_ * 2);
    bf16*  kbuf = (bf16*)take((size_t)T_ * D_ * 2);
    bf16*  vbuf = (bf16*)take((size_t)T_ * D_ * 2);
    bf16*  aob  = (bf16*)take((size_t)T_ * D_ * 2);
    bf16*  ub   = (bf16*)take((size_t)T_ * FF_ * 2);
    int*   top  = (int*)take((size_t)T_ * 4);
    float* wsel = (float*)take((size_t)T_ * 4);
    (void)ws_size; (void)in_sizes; (void)n_in; (void)out_size;

    // weight prep (every call; ws is re-poisoned by harness)
    transpose_cast<<<dim3(D_ / 32, D_ / 32), 256, 0, stream>>>(Wq, WqT, D_, D_);
    transpose_cast<<<dim3(D_ / 32, D_ / 32), 256, 0, stream>>>(Wk, WkT, D_, D_);
    transpose_cast<<<dim3(D_ / 32, D_ / 32), 256, 0, stream>>>(Wv, WvT, D_, D_);
    transpose_cast<<<dim3(D_ / 32, D_ / 32), 256, 0, stream>>>(Wo, WoT, D_, D_);
    transpose_cast<<<dim3(FF_ / 32, D_ / 32), 256, 0, stream>>>(Wg, WgT, D_, FF_);
    transpose_cast<<<dim3(FF_ / 32, D_ / 32), 256, 0, stream>>>(Wu, WuT, D_, FF_);
    transpose_cast<<<dim3(D_ / 32, FF_ / 32), 256, 0, stream>>>(Wd, WdT, FF_, D_);

    router_k<<<T_ / 4, 256, 0, stream>>>(x, wrt, top, wsel);

    const float* cur_in = x;   // recursion-0 input is x itself
    for (int rec = 0; rec < R_; rec++) {
        rmsnorm_k<<<T_, 256, 0, stream>>>(cur_in, ln1, hb);
        // fused QKV (z selects weight/output)
        gemm_k<0><<<dim3(T_ / 128, D_ / 128, 3), 256, 0, stream>>>(
            hb, WqT, WkT, WvT, qb, kbuf, vbuf,
            nullptr, nullptr, nullptr, nullptr, nullptr, nullptr, nullptr, nullptr, 0, D_, D_);
        rope_k<<<(T_ * H_ * 64) / 256, 256, 0, stream>>>(qb, kbuf, cosb, sinb);
        attn_k<<<dim3(S_ / 16, H_, B_), 256, 0, stream>>>(qb, kbuf, vbuf, top, rec, aob);
        // O proj + residual -> xnew
        gemm_k<1><<<dim3(T_ / 128, D_ / 128, 1), 256, 0, stream>>>(
            aob, WoT, nullptr, nullptr, nullptr, nullptr, nullptr,
            cur_in, xnew, nullptr, nullptr, nullptr, nullptr, nullptr, nullptr, 0, D_, D_);
        rmsnorm_k<<<T_, 256, 0, stream>>>(xnew, ln2, hb);
        // u = h2 @ Wu
        gemm_k<0><<<dim3(T_ / 128, FF_ / 128, 1), 256, 0, stream>>>(
            hb, WuT, nullptr, nullptr, ub, nullptr, nullptr,
            nullptr, nullptr, nullptr, nullptr, nullptr, nullptr, nullptr, nullptr, 0, FF_, D_);
        // t = silu(h2 @ Wg) * u   (in-place on ub)
        gemm_k<2><<<dim3(T_ / 128, FF_ / 128, 1), 256, 0, stream>>>(
            hb, WgT, nullptr, nullptr, nullptr, nullptr, nullptr,
            nullptr, nullptr, ub, ub, nullptr, nullptr, nullptr, nullptr, 0, FF_, D_);
        // down proj + residual + fused MoR routing update (final / cur)
        gemm_k<3><<<dim3(T_ / 128, D_ / 128, 1), 256, 0, stream>>>(
            ub, WdT, nullptr, nullptr, nullptr, nullptr, nullptr,
            xnew, nullptr, nullptr, nullptr, top, wsel, (float*)d_out, cur, rec, D_, FF_);
        cur_in = cur;
    }
}

// Round 5
// 2220.351 us; speedup vs baseline: 1.4386x; 1.4386x over previous
//
#include <hip/hip_runtime.h>
#include <hip/hip_bf16.h>

// Problem constants (MoR Llama decoder layer)
#define B_  2
#define S_  1024
#define D_  2048
#define H_  16
#define HD_ 128
#define FF_ 8192
#define R_  3
#define T_  (B_*S_)

typedef __attribute__((ext_vector_type(8))) short bf16x8;   // 8 x bf16 (4 VGPR) MFMA frag
typedef __attribute__((ext_vector_type(4))) float f32x4;    // MFMA accumulator
using bf16 = __hip_bfloat16;

// ---------- helpers ----------
__device__ __forceinline__ float bf2f(short s) {
    return __uint_as_float(((unsigned)(unsigned short)s) << 16);
}
__device__ __forceinline__ unsigned f2bf_bits(float f) {
    bf16 h = __float2bfloat16(f);
    unsigned short u; __builtin_memcpy(&u, &h, 2);
    return (unsigned)u;
}
__device__ __forceinline__ unsigned pack2(float a, float b) {
    return f2bf_bits(a) | (f2bf_bits(b) << 16);
}
__device__ __forceinline__ float wsum(float v) {
    #pragma unroll
    for (int m = 32; m; m >>= 1) v += __shfl_xor(v, m);
    return v;
}
__device__ __forceinline__ void load_lds16(const void* g, void* l) {
    // async global->LDS, 16B per lane; LDS dest is wave-uniform base + lane*16
    __builtin_amdgcn_global_load_lds((const __attribute__((address_space(1))) void*)g,
                                     (__attribute__((address_space(3))) void*)l, 16, 0, 0);
}

// ---------- weight transpose+cast: W[K][N] f32 -> Wt[N][K] bf16 ----------
__global__ __launch_bounds__(256)
void transpose_cast(const float* __restrict__ W, bf16* __restrict__ Wt, int K, int N) {
    __shared__ float tile[32][33];
    const int n0 = blockIdx.x * 32, k0 = blockIdx.y * 32;
    const int c = threadIdx.x & 31, r8 = threadIdx.x >> 5;
    #pragma unroll
    for (int i = 0; i < 4; i++) {
        int r = r8 + i * 8;
        tile[r][c] = W[(long)(k0 + r) * N + n0 + c];
    }
    __syncthreads();
    #pragma unroll
    for (int i = 0; i < 4; i++) {
        int r = r8 + i * 8;
        Wt[(long)(n0 + r) * K + k0 + c] = __float2bfloat16(tile[c][r]);
    }
}

// ---------- router ----------
__global__ __launch_bounds__(256)
void router_k(const float* __restrict__ X, const float* __restrict__ Wr,
              int* __restrict__ top, float* __restrict__ wsel) {
    const int t = blockIdx.x * 4 + (threadIdx.x >> 6);
    const int lane = threadIdx.x & 63;
    const float* x = X + (long)t * D_;
    float a0 = 0.f, a1 = 0.f, a2 = 0.f;
    for (int j = lane; j < D_; j += 64) {
        float xv = x[j];
        a0 += xv * Wr[j * 3 + 0];
        a1 += xv * Wr[j * 3 + 1];
        a2 += xv * Wr[j * 3 + 2];
    }
    a0 = wsum(a0); a1 = wsum(a1); a2 = wsum(a2);
    if (lane == 0) {
        int arg = 0; float bm = a0;
        if (a1 > bm) { bm = a1; arg = 1; }
        if (a2 > bm) { bm = a2; arg = 2; }
        float s = expf(a0 - bm) + expf(a1 - bm) + expf(a2 - bm);
        top[t]  = arg;
        wsel[t] = 1.0f / s;   // softmax value at argmax (TEMP=ALPHA=1)
    }
}

// ---------- RMSNorm f32 -> bf16 ----------
__global__ __launch_bounds__(256)
void rmsnorm_k(const float* __restrict__ X, const float* __restrict__ G, bf16* __restrict__ Hb) {
    const int t = blockIdx.x, tid = threadIdx.x;
    const float4* xr = (const float4*)(X + (long)t * D_);
    float4 v0 = xr[tid], v1 = xr[tid + 256];
    float ss = v0.x*v0.x + v0.y*v0.y + v0.z*v0.z + v0.w*v0.w
             + v1.x*v1.x + v1.y*v1.y + v1.z*v1.z + v1.w*v1.w;
    ss = wsum(ss);
    __shared__ float red[4];
    if ((tid & 63) == 0) red[tid >> 6] = ss;
    __syncthreads();
    const float r = rsqrtf((red[0] + red[1] + red[2] + red[3]) * (1.0f / D_) + 1e-6f);
    const float4* gr = (const float4*)G;
    float4 g0 = gr[tid], g1 = gr[tid + 256];
    uint2* ob = (uint2*)(Hb + (long)t * D_);
    uint2 o;
    o.x = pack2(v0.x * r * g0.x, v0.y * r * g0.y);
    o.y = pack2(v0.z * r * g0.z, v0.w * r * g0.w);
    ob[tid] = o;
    o.x = pack2(v1.x * r * g1.x, v1.y * r * g1.y);
    o.y = pack2(v1.z * r * g1.z, v1.w * r * g1.w);
    ob[tid + 256] = o;
}

// ---------- RoPE in-place on q,k ----------
__global__ __launch_bounds__(256)
void rope_k(bf16* __restrict__ q, bf16* __restrict__ k,
            const float* __restrict__ cosb, const float* __restrict__ sinb) {
    const int idx = blockIdx.x * 256 + threadIdx.x;   // T*H*64 threads
    const int d = idx & 63;
    const int h = (idx >> 6) & (H_ - 1);
    const int t = idx >> 10;
    const int s = t & (S_ - 1);
    const long base = (long)t * D_ + h * HD_;
    const float c1 = cosb[s * HD_ + d],      s1 = sinb[s * HD_ + d];
    const float c2 = cosb[s * HD_ + d + 64], s2 = sinb[s * HD_ + d + 64];
    float q1 = __bfloat162float(q[base + d]), q2 = __bfloat162float(q[base + d + 64]);
    q[base + d]      = __float2bfloat16(q1 * c1 - q2 * s1);
    q[base + d + 64] = __float2bfloat16(q2 * c2 + q1 * s2);
    float k1 = __bfloat162float(k[base + d]), k2 = __bfloat162float(k[base + d + 64]);
    k[base + d]      = __float2bfloat16(k1 * c1 - k2 * s1);
    k[base + d + 64] = __float2bfloat16(k2 * c2 + k1 * s2);
}

// ---------- MFMA flash attention ----------
// grid (S/64, H, B); block 256 = 4 waves; wave owns 16 queries (qw = q0 + w*16).
// QK^T: A=Q(16x32), B=K^T -> S-acc col=key(lane&15 within group), row=q((lane>>4)*4+j)
// PV:   O^T = V^T @ P^T : A=V^T(16d x 32k), B=P^T -> O-acc col=q(lane&15), row=d
__global__ __launch_bounds__(256)
void attn_k(const bf16* __restrict__ qb, const bf16* __restrict__ kb, const bf16* __restrict__ vb,
            const int* __restrict__ top, int rec, bf16* __restrict__ aob) {
    __shared__ bf16 Ks[64 * 128];        // row=key, 16B-chunk swizzle: chunk^=(row&7)
    __shared__ unsigned Vt[128 * 32];    // Vt[d][keypair] {k=2p lo, 2p+1 hi}; chunk^=((d^(d>>3))&7)
    __shared__ unsigned short Pt[4][64 * 16];  // per-wave P^T[key][q] bf16 bits
    const int tid = threadIdx.x, w = tid >> 6, lane = tid & 63;
    const int l15 = lane & 15, lg = lane >> 4;
    const int q0 = blockIdx.x * 64;
    const int h = blockIdx.y, b = blockIdx.z;
    const int qw = q0 + w * 16;

    // Q fragments in registers: Qf[ds] = Q[qw+l15][ds*32 + lg*8 .. +8]
    bf16x8 Qf[4];
    {
        const bf16* qptr = qb + ((long)((b * S_ + qw + l15) * H_ + h)) * HD_ + lg * 8;
        #pragma unroll
        for (int ds = 0; ds < 4; ds++) Qf[ds] = *(const bf16x8*)(qptr + ds * 32);
    }

    f32x4 oacc[8] = {};               // O^T: col=q(l15), row=d_rel(lg*4+j), 8 d-groups
    float mrow[4] = {-1e30f, -1e30f, -1e30f, -1e30f};
    float lrow[4] = {0.f, 0.f, 0.f, 0.f};
    const float rs = 0.088388347648318447f;   // 1/sqrt(128)
    const int bsrc = (l15 >> 2) << 4;         // broadcast source lane for q=l15
    const int jj = l15 & 3;

    const int nch = blockIdx.x + 1;           // causal: chunks 0..q0/64
    for (int kc = 0; kc < nch; kc++) {
        __syncthreads();
        // ---- stage K via global_load_lds (pre-swizzled global source, linear LDS dest)
        #pragma unroll
        for (int i = 0; i < 4; i++) {
            int r = w * 16 + i * 4 + lg;          // LDS row this lane covers
            int key = kc * 64 + r;
            const bf16* src = kb + ((long)((b * S_ + key) * H_ + h)) * HD_ + ((l15 ^ (r & 7)) * 8);
            load_lds16(src, &Ks[(w * 16 + i * 4) * 128]);
        }
        // ---- stage V transposed+pair-packed into Vt (reg-staged)
        #pragma unroll
        for (int i = 0; i < 2; i++) {
            int j = i * 256 + tid;
            int c = j & 15, r2 = (j >> 4) & 31;   // d-chunk, key-pair
            long gv = ((long)((b * S_ + kc * 64 + 2 * r2) * H_ + h)) * HD_ + c * 8;
            uint4 va = *(const uint4*)&vb[gv];
            uint4 vbn = *(const uint4*)&vb[gv + D_];
            const unsigned short* pa = (const unsigned short*)&va;
            const unsigned short* pb = (const unsigned short*)&vbn;
            #pragma unroll
            for (int e = 0; e < 8; e++) {
                int d = c * 8 + e;
                int sw = (d ^ (d >> 3)) & 7;
                Vt[d * 32 + (((r2 >> 2) ^ sw) << 2) + (r2 & 3)] =
                    (unsigned)pa[e] | ((unsigned)pb[e] << 16);
            }
        }
        __syncthreads();

        // ---- QK^T (16 MFMA)
        f32x4 sacc[4] = {};
        #pragma unroll
        for (int kg = 0; kg < 4; kg++) {
            const int row = kg * 16 + l15;
            #pragma unroll
            for (int ds = 0; ds < 4; ds++) {
                bf16x8 kf = *(const bf16x8*)&Ks[row * 128 + (((ds * 4 + lg) ^ (row & 7)) * 8)];
                sacc[kg] = __builtin_amdgcn_mfma_f32_16x16x32_bf16(Qf[ds], kf, sacc[kg], 0, 0, 0);
            }
        }

        // ---- mask + online softmax (per lane: 4 keys (kg) x 4 q-rows (j))
        int selm[4];
        #pragma unroll
        for (int kg = 0; kg < 4; kg++) {
            int key = kc * 64 + kg * 16 + l15;
            selm[kg] = (top[b * S_ + key] >= rec) ? (key) : (1 << 30);  // masked -> huge key
        }
        float pmat[4][4];
        #pragma unroll
        for (int kg = 0; kg < 4; kg++) {
            #pragma unroll
            for (int j = 0; j < 4; j++) {
                float s = sacc[kg][j] * rs;
                pmat[kg][j] = (selm[kg] <= qw + lg * 4 + j) ? s : -1e9f;
            }
        }
        float scj[4];
        #pragma unroll
        for (int j = 0; j < 4; j++) {
            float tm = fmaxf(fmaxf(pmat[0][j], pmat[1][j]), fmaxf(pmat[2][j], pmat[3][j]));
            #pragma unroll
            for (int m = 1; m < 16; m <<= 1) tm = fmaxf(tm, __shfl_xor(tm, m));
            float mnew = fmaxf(mrow[j], tm);
            scj[j] = __expf(mrow[j] - mnew);
            mrow[j] = mnew;
            float ps = 0.f;
            #pragma unroll
            for (int kg = 0; kg < 4; kg++) {
                float p = __expf(pmat[kg][j] - mnew);
                pmat[kg][j] = p;
                ps += p;
            }
            #pragma unroll
            for (int m = 1; m < 16; m <<= 1) ps += __shfl_xor(ps, m);
            lrow[j] = lrow[j] * scj[j] + ps;
        }
        // write P^T to per-wave LDS: row=key_rel(kg*16+l15), cols q=lg*4..+3
        #pragma unroll
        for (int kg = 0; kg < 4; kg++) {
            uint2 u;
            u.x = pack2(pmat[kg][0], pmat[kg][1]);
            u.y = pack2(pmat[kg][2], pmat[kg][3]);
            *(uint2*)&Pt[w][(kg * 16 + l15) * 16 + lg * 4] = u;
        }
        // rescale O-acc by sc for q=l15 (broadcast from softmax owner lanes)
        {
            float t0 = __shfl(scj[0], bsrc), t1 = __shfl(scj[1], bsrc);
            float t2 = __shfl(scj[2], bsrc), t3 = __shfl(scj[3], bsrc);
            float scq = (jj == 0) ? t0 : (jj == 1) ? t1 : (jj == 2) ? t2 : t3;
            #pragma unroll
            for (int dg = 0; dg < 8; dg++) {
                oacc[dg][0] *= scq; oacc[dg][1] *= scq;
                oacc[dg][2] *= scq; oacc[dg][3] *= scq;
            }
        }
        // ---- PV (16 MFMA): O^T += V^T @ P^T
        #pragma unroll
        for (int ks = 0; ks < 2; ks++) {
            bf16x8 pf;
            #pragma unroll
            for (int e = 0; e < 8; e++)
                pf[e] = (short)Pt[w][(ks * 32 + lg * 8 + e) * 16 + l15];
            #pragma unroll
            for (int dg = 0; dg < 8; dg++) {
                int d = dg * 16 + l15;
                int sw = (d ^ (d >> 3)) & 7;
                bf16x8 vf = *(const bf16x8*)&Vt[d * 32 + (((ks * 4 + lg) ^ sw) << 2)];
                oacc[dg] = __builtin_amdgcn_mfma_f32_16x16x32_bf16(vf, pf, oacc[dg], 0, 0, 0);
            }
        }
    }
    // ---- epilogue: divide by l (broadcast per q=l15), store O^T -> aob[token][h][d]
    float u0 = __shfl(lrow[0], bsrc), u1 = __shfl(lrow[1], bsrc);
    float u2 = __shfl(lrow[2], bsrc), u3 = __shfl(lrow[3], bsrc);
    float lq = (jj == 0) ? u0 : (jj == 1) ? u1 : (jj == 2) ? u2 : u3;
    float li = 1.0f / lq;
    const long obase = ((long)((b * S_ + qw + l15) * H_ + h)) * HD_ + lg * 4;
    #pragma unroll
    for (int dg = 0; dg < 8; dg++) {
        #pragma unroll
        for (int jp = 0; jp < 2; jp++) {
            unsigned o = pack2(oacc[dg][jp * 2] * li, oacc[dg][jp * 2 + 1] * li);
            *(unsigned*)&aob[obase + dg * 16 + jp * 2] = o;
        }
    }
}

// ---------- bf16 MFMA GEMM (m97 structure + T1 XCD swizzle): C = A[M][K] @ Bt[N][K]^T ----------
template<int EP>
__global__ __launch_bounds__(256)
void gemm_k(const bf16* __restrict__ A,
            const bf16* __restrict__ Bt0, const bf16* __restrict__ Bt1, const bf16* __restrict__ Bt2,
            bf16* __restrict__ C0, bf16* __restrict__ C1, bf16* __restrict__ C2,
            const float* __restrict__ resid, float* __restrict__ xout,
            const bf16* __restrict__ uaux, bf16* __restrict__ taux,
            const int* __restrict__ topidx, const float* __restrict__ wsel,
            float* __restrict__ finalp, float* __restrict__ curp, int rec,
            int N, int K) {
    __shared__ bf16 As[128 * 32];
    __shared__ bf16 Bs[128 * 32];
    const int tid = threadIdx.x;
    const int w = tid >> 6, lane = tid & 63;

    // T1: XCD-aware bijective swizzle (m204). HW places dispatch-id i on XCD i%8;
    // remap so each XCD's blocks form a contiguous run of tiles (L2 panel reuse).
    const int gx = gridDim.x;
    const int nwg = gx * gridDim.y;
    const int orig = blockIdx.y * gx + blockIdx.x;
    const int qc = nwg >> 3, rc = nwg & 7;
    const int xcd = orig & 7, loc = orig >> 3;
    const int wg = (xcd < rc ? xcd * (qc + 1) : rc * (qc + 1) + (xcd - rc) * qc) + loc;
    const int m0 = (wg % gx) * 128, n0 = (wg / gx) * 128;

    const bf16* Bt = (blockIdx.z == 0) ? Bt0 : ((blockIdx.z == 1) ? Bt1 : Bt2);
    bf16* Cb       = (blockIdx.z == 0) ? C0  : ((blockIdx.z == 1) ? C1  : C2);

    const int srow = lane >> 2;
    const int scol = (lane & 3) * 8;
    const long gA = (long)(m0 + w * 32 + srow) * K + scol;
    const long gB = (long)(n0 + w * 32 + srow) * K + scol;

    const int wr = w >> 1, wc = w & 1;
    const int fm = lane & 15, kg = lane >> 4;

    f32x4 acc[4][4] = {};

    for (int kt = 0; kt < K; kt += 32) {
        __syncthreads();
        #pragma unroll
        for (int i = 0; i < 2; i++) {
            load_lds16(A  + gA + (long)(16 * i) * K + kt, &As[(w * 32 + 16 * i) * 32]);
            load_lds16(Bt + gB + (long)(16 * i) * K + kt, &Bs[(w * 32 + 16 * i) * 32]);
        }
        __syncthreads();
        bf16x8 af[4], bfr[4];
        #pragma unroll
        for (int mi = 0; mi < 4; mi++)
            af[mi] = *(const bf16x8*)&As[(wr * 64 + mi * 16 + fm) * 32 + kg * 8];
        #pragma unroll
        for (int ni = 0; ni < 4; ni++)
            bfr[ni] = *(const bf16x8*)&Bs[(wc * 64 + ni * 16 + fm) * 32 + kg * 8];
        #pragma unroll
        for (int mi = 0; mi < 4; mi++)
            #pragma unroll
            for (int ni = 0; ni < 4; ni++)
                acc[mi][ni] = __builtin_amdgcn_mfma_f32_16x16x32_bf16(af[mi], bfr[ni], acc[mi][ni], 0, 0, 0);
    }
    #pragma unroll
    for (int mi = 0; mi < 4; mi++) {
        #pragma unroll
        for (int j = 0; j < 4; j++) {
            const int m = m0 + wr * 64 + mi * 16 + kg * 4 + j;
            int   ti = 0; float wv = 0.f;
            if (EP == 3) { ti = topidx[m]; wv = wsel[m]; }
            #pragma unroll
            for (int ni = 0; ni < 4; ni++) {
                const int n = n0 + wc * 64 + ni * 16 + fm;
                const long off = (long)m * N + n;
                float v = acc[mi][ni][j];
                if (EP == 0) {
                    Cb[off] = __float2bfloat16(v);
                } else if (EP == 1) {
                    xout[off] = v + resid[off];
                } else if (EP == 2) {
                    float u = __bfloat162float(uaux[off]);
                    taux[off] = __float2bfloat16(u * v / (1.f + __expf(-v)));
                } else {
                    float o = v + resid[off];
                    if (ti == rec) finalp[off] = o * wv;
                    if (ti >= rec) curp[off] = o;
                }
            }
        }
    }
}

// ---------- host ----------
extern "C" void kernel_launch(void* const* d_in, const int* in_sizes, int n_in,
                              void* d_out, int out_size, void* d_ws, size_t ws_size,
                              hipStream_t stream) {
    const float* x    = (const float*)d_in[0];
    const float* cosb = (const float*)d_in[1];
    const float* sinb = (const float*)d_in[2];
    const float* wrt  = (const float*)d_in[3];
    const float* ln1  = (const float*)d_in[4];
    const float* ln2  = (const float*)d_in[5];
    const float* Wq   = (const float*)d_in[6];
    const float* Wk   = (const float*)d_in[7];
    const float* Wv   = (const float*)d_in[8];
    const float* Wo   = (const float*)d_in[9];
    const float* Wg   = (const float*)d_in[10];
    const float* Wu   = (const float*)d_in[11];
    const float* Wd   = (const float*)d_in[12];

    char* p = (char*)d_ws;
    auto take = [&](size_t bytes) -> char* {
        char* r = p; p += (bytes + 255) & ~(size_t)255; return r;
    };
    bf16* WqT = (bf16*)take((size_t)D_ * D_ * 2);
    bf16* WkT = (bf16*)take((size_t)D_ * D_ * 2);
    bf16* WvT = (bf16*)take((size_t)D_ * D_ * 2);
    bf16* WoT = (bf16*)take((size_t)D_ * D_ * 2);
    bf16* WgT = (bf16*)take((size_t)D_ * FF_ * 2);
    bf16* WuT = (bf16*)take((size_t)D_ * FF_ * 2);
    bf16* WdT = (bf16*)take((size_t)D_ * FF_ * 2);
    float* cur  = (float*)take((size_t)T_ * D_ * 4);
    float* xnew = (float*)take((size_t)T_ * D_ * 4);
    bf16*  hb   = (bf16*)take((size_t)T_ * D_ * 2);
    bf16*  qb   = (bf16*)take((size_t)T_ * D_ * 2);
    bf16*  kbuf = (bf16*)take((size_t)T_ * D_ * 2);
    bf16*  vbuf = (bf16*)take((size_t)T_ * D_ * 2);
    bf16*  aob  = (bf16*)take((size_t)T_ * D_ * 2);
    bf16*  ub   = (bf16*)take((size_t)T_ * FF_ * 2);
    int*   top  = (int*)take((size_t)T_ * 4);
    float* wsel = (float*)take((size_t)T_ * 4);
    (void)ws_size; (void)in_sizes; (void)n_in; (void)out_size;

    transpose_cast<<<dim3(D_ / 32, D_ / 32), 256, 0, stream>>>(Wq, WqT, D_, D_);
    transpose_cast<<<dim3(D_ / 32, D_ / 32), 256, 0, stream>>>(Wk, WkT, D_, D_);
    transpose_cast<<<dim3(D_ / 32, D_ / 32), 256, 0, stream>>>(Wv, WvT, D_, D_);
    transpose_cast<<<dim3(D_ / 32, D_ / 32), 256, 0, stream>>>(Wo, WoT, D_, D_);
    transpose_cast<<<dim3(FF_ / 32, D_ / 32), 256, 0, stream>>>(Wg, WgT, D_, FF_);
    transpose_cast<<<dim3(FF_ / 32, D_ / 32), 256, 0, stream>>>(Wu, WuT, D_, FF_);
    transpose_cast<<<dim3(D_ / 32, FF_ / 32), 256, 0, stream>>>(Wd, WdT, FF_, D_);

    router_k<<<T_ / 4, 256, 0, stream>>>(x, wrt, top, wsel);

    const float* cur_in = x;
    for (int rec = 0; rec < R_; rec++) {
        rmsnorm_k<<<T_, 256, 0, stream>>>(cur_in, ln1, hb);
        gemm_k<0><<<dim3(T_ / 128, D_ / 128, 3), 256, 0, stream>>>(
            hb, WqT, WkT, WvT, qb, kbuf, vbuf,
            nullptr, nullptr, nullptr, nullptr, nullptr, nullptr, nullptr, nullptr, 0, D_, D_);
        rope_k<<<(T_ * H_ * 64) / 256, 256, 0, stream>>>(qb, kbuf, cosb, sinb);
        attn_k<<<dim3(S_ / 64, H_, B_), 256, 0, stream>>>(qb, kbuf, vbuf, top, rec, aob);
        gemm_k<1><<<dim3(T_ / 128, D_ / 128, 1), 256, 0, stream>>>(
            aob, WoT, nullptr, nullptr, nullptr, nullptr, nullptr,
            cur_in, xnew, nullptr, nullptr, nullptr, nullptr, nullptr, nullptr, 0, D_, D_);
        rmsnorm_k<<<T_, 256, 0, stream>>>(xnew, ln2, hb);
        gemm_k<0><<<dim3(T_ / 128, FF_ / 128, 1), 256, 0, stream>>>(
            hb, WuT, nullptr, nullptr, ub, nullptr, nullptr,
            nullptr, nullptr, nullptr, nullptr, nullptr, nullptr, nullptr, nullptr, 0, FF_, D_);
        gemm_k<2><<<dim3(T_ / 128, FF_ / 128, 1), 256, 0, stream>>>(
            hb, WgT, nullptr, nullptr, nullptr, nullptr, nullptr,
            nullptr, nullptr, ub, ub, nullptr, nullptr, nullptr, nullptr, 0, FF_, D_);
        gemm_k<3><<<dim3(T_ / 128, D_ / 128, 1), 256, 0, stream>>>(
            ub, WdT, nullptr, nullptr, nullptr, nullptr, nullptr,
            xnew, nullptr, nullptr, nullptr, top, wsel, (float*)d_out, cur, rec, D_, FF_);
        cur_in = cur;
    }
}

// Round 6
// 1958.587 us; speedup vs baseline: 1.6308x; 1.1336x over previous
//
#include <hip/hip_runtime.h>
#include <hip/hip_bf16.h>

// Problem constants (MoR Llama decoder layer)
#define B_  2
#define S_  1024
#define D_  2048
#define H_  16
#define HD_ 128
#define FF_ 8192
#define R_  3
#define T_  (B_*S_)

typedef __attribute__((ext_vector_type(8))) short bf16x8;   // 8 x bf16 (4 VGPR) MFMA frag
typedef __attribute__((ext_vector_type(4))) float f32x4;    // MFMA accumulator
using bf16 = __hip_bfloat16;

// ---------- helpers ----------
__device__ __forceinline__ float bf2f(short s) {
    return __uint_as_float(((unsigned)(unsigned short)s) << 16);
}
__device__ __forceinline__ unsigned f2bf_bits(float f) {
    bf16 h = __float2bfloat16(f);
    unsigned short u; __builtin_memcpy(&u, &h, 2);
    return (unsigned)u;
}
__device__ __forceinline__ unsigned pack2(float a, float b) {
    return f2bf_bits(a) | (f2bf_bits(b) << 16);
}
__device__ __forceinline__ float wsum(float v) {
    #pragma unroll
    for (int m = 32; m; m >>= 1) v += __shfl_xor(v, m);
    return v;
}
__device__ __forceinline__ void load_lds16(const void* g, void* l) {
    // async global->LDS, 16B per lane; LDS dest is wave-uniform base + lane*16
    __builtin_amdgcn_global_load_lds((const __attribute__((address_space(1))) void*)g,
                                     (__attribute__((address_space(3))) void*)l, 16, 0, 0);
}

// ---------- weight transpose+cast: W[K][N] f32 -> Wt[N][K] bf16 ----------
__global__ __launch_bounds__(256)
void transpose_cast(const float* __restrict__ W, bf16* __restrict__ Wt, int K, int N) {
    __shared__ float tile[32][33];
    const int n0 = blockIdx.x * 32, k0 = blockIdx.y * 32;
    const int c = threadIdx.x & 31, r8 = threadIdx.x >> 5;
    #pragma unroll
    for (int i = 0; i < 4; i++) {
        int r = r8 + i * 8;
        tile[r][c] = W[(long)(k0 + r) * N + n0 + c];
    }
    __syncthreads();
    #pragma unroll
    for (int i = 0; i < 4; i++) {
        int r = r8 + i * 8;
        Wt[(long)(n0 + r) * K + k0 + c] = __float2bfloat16(tile[c][r]);
    }
}

// ---------- router ----------
__global__ __launch_bounds__(256)
void router_k(const float* __restrict__ X, const float* __restrict__ Wr,
              int* __restrict__ top, float* __restrict__ wsel) {
    const int t = blockIdx.x * 4 + (threadIdx.x >> 6);
    const int lane = threadIdx.x & 63;
    const float* x = X + (long)t * D_;
    float a0 = 0.f, a1 = 0.f, a2 = 0.f;
    for (int j = lane; j < D_; j += 64) {
        float xv = x[j];
        a0 += xv * Wr[j * 3 + 0];
        a1 += xv * Wr[j * 3 + 1];
        a2 += xv * Wr[j * 3 + 2];
    }
    a0 = wsum(a0); a1 = wsum(a1); a2 = wsum(a2);
    if (lane == 0) {
        int arg = 0; float bm = a0;
        if (a1 > bm) { bm = a1; arg = 1; }
        if (a2 > bm) { bm = a2; arg = 2; }
        float s = expf(a0 - bm) + expf(a1 - bm) + expf(a2 - bm);
        top[t]  = arg;
        wsel[t] = 1.0f / s;   // softmax value at argmax (TEMP=ALPHA=1)
    }
}

// ---------- RMSNorm f32 -> bf16 ----------
__global__ __launch_bounds__(256)
void rmsnorm_k(const float* __restrict__ X, const float* __restrict__ G, bf16* __restrict__ Hb) {
    const int t = blockIdx.x, tid = threadIdx.x;
    const float4* xr = (const float4*)(X + (long)t * D_);
    float4 v0 = xr[tid], v1 = xr[tid + 256];
    float ss = v0.x*v0.x + v0.y*v0.y + v0.z*v0.z + v0.w*v0.w
             + v1.x*v1.x + v1.y*v1.y + v1.z*v1.z + v1.w*v1.w;
    ss = wsum(ss);
    __shared__ float red[4];
    if ((tid & 63) == 0) red[tid >> 6] = ss;
    __syncthreads();
    const float r = rsqrtf((red[0] + red[1] + red[2] + red[3]) * (1.0f / D_) + 1e-6f);
    const float4* gr = (const float4*)G;
    float4 g0 = gr[tid], g1 = gr[tid + 256];
    uint2* ob = (uint2*)(Hb + (long)t * D_);
    uint2 o;
    o.x = pack2(v0.x * r * g0.x, v0.y * r * g0.y);
    o.y = pack2(v0.z * r * g0.z, v0.w * r * g0.w);
    ob[tid] = o;
    o.x = pack2(v1.x * r * g1.x, v1.y * r * g1.y);
    o.y = pack2(v1.z * r * g1.z, v1.w * r * g1.w);
    ob[tid + 256] = o;
}

// ---------- RoPE in-place on q,k ----------
__global__ __launch_bounds__(256)
void rope_k(bf16* __restrict__ q, bf16* __restrict__ k,
            const float* __restrict__ cosb, const float* __restrict__ sinb) {
    const int idx = blockIdx.x * 256 + threadIdx.x;   // T*H*64 threads
    const int d = idx & 63;
    const int h = (idx >> 6) & (H_ - 1);
    const int t = idx >> 10;
    const int s = t & (S_ - 1);
    const long base = (long)t * D_ + h * HD_;
    const float c1 = cosb[s * HD_ + d],      s1 = sinb[s * HD_ + d];
    const float c2 = cosb[s * HD_ + d + 64], s2 = sinb[s * HD_ + d + 64];
    float q1 = __bfloat162float(q[base + d]), q2 = __bfloat162float(q[base + d + 64]);
    q[base + d]      = __float2bfloat16(q1 * c1 - q2 * s1);
    q[base + d + 64] = __float2bfloat16(q2 * c2 + q1 * s2);
    float k1 = __bfloat162float(k[base + d]), k2 = __bfloat162float(k[base + d + 64]);
    k[base + d]      = __float2bfloat16(k1 * c1 - k2 * s1);
    k[base + d + 64] = __float2bfloat16(k2 * c2 + k1 * s2);
}

// ---------- MFMA flash attention (unchanged, verified round 5) ----------
__global__ __launch_bounds__(256)
void attn_k(const bf16* __restrict__ qb, const bf16* __restrict__ kb, const bf16* __restrict__ vb,
            const int* __restrict__ top, int rec, bf16* __restrict__ aob) {
    __shared__ bf16 Ks[64 * 128];        // row=key, 16B-chunk swizzle: chunk^=(row&7)
    __shared__ unsigned Vt[128 * 32];    // Vt[d][keypair]; chunk^=((d^(d>>3))&7)
    __shared__ unsigned short Pt[4][64 * 16];  // per-wave P^T[key][q] bf16 bits
    const int tid = threadIdx.x, w = tid >> 6, lane = tid & 63;
    const int l15 = lane & 15, lg = lane >> 4;
    const int q0 = blockIdx.x * 64;
    const int h = blockIdx.y, b = blockIdx.z;
    const int qw = q0 + w * 16;

    bf16x8 Qf[4];
    {
        const bf16* qptr = qb + ((long)((b * S_ + qw + l15) * H_ + h)) * HD_ + lg * 8;
        #pragma unroll
        for (int ds = 0; ds < 4; ds++) Qf[ds] = *(const bf16x8*)(qptr + ds * 32);
    }

    f32x4 oacc[8] = {};
    float mrow[4] = {-1e30f, -1e30f, -1e30f, -1e30f};
    float lrow[4] = {0.f, 0.f, 0.f, 0.f};
    const float rs = 0.088388347648318447f;   // 1/sqrt(128)
    const int bsrc = (l15 >> 2) << 4;
    const int jj = l15 & 3;

    const int nch = blockIdx.x + 1;
    for (int kc = 0; kc < nch; kc++) {
        __syncthreads();
        #pragma unroll
        for (int i = 0; i < 4; i++) {
            int r = w * 16 + i * 4 + lg;
            int key = kc * 64 + r;
            const bf16* src = kb + ((long)((b * S_ + key) * H_ + h)) * HD_ + ((l15 ^ (r & 7)) * 8);
            load_lds16(src, &Ks[(w * 16 + i * 4) * 128]);
        }
        #pragma unroll
        for (int i = 0; i < 2; i++) {
            int j = i * 256 + tid;
            int c = j & 15, r2 = (j >> 4) & 31;
            long gv = ((long)((b * S_ + kc * 64 + 2 * r2) * H_ + h)) * HD_ + c * 8;
            uint4 va = *(const uint4*)&vb[gv];
            uint4 vbn = *(const uint4*)&vb[gv + D_];
            const unsigned short* pa = (const unsigned short*)&va;
            const unsigned short* pb = (const unsigned short*)&vbn;
            #pragma unroll
            for (int e = 0; e < 8; e++) {
                int d = c * 8 + e;
                int sw = (d ^ (d >> 3)) & 7;
                Vt[d * 32 + (((r2 >> 2) ^ sw) << 2) + (r2 & 3)] =
                    (unsigned)pa[e] | ((unsigned)pb[e] << 16);
            }
        }
        __syncthreads();

        f32x4 sacc[4] = {};
        #pragma unroll
        for (int kg = 0; kg < 4; kg++) {
            const int row = kg * 16 + l15;
            #pragma unroll
            for (int ds = 0; ds < 4; ds++) {
                bf16x8 kf = *(const bf16x8*)&Ks[row * 128 + (((ds * 4 + lg) ^ (row & 7)) * 8)];
                sacc[kg] = __builtin_amdgcn_mfma_f32_16x16x32_bf16(Qf[ds], kf, sacc[kg], 0, 0, 0);
            }
        }

        int selm[4];
        #pragma unroll
        for (int kg = 0; kg < 4; kg++) {
            int key = kc * 64 + kg * 16 + l15;
            selm[kg] = (top[b * S_ + key] >= rec) ? (key) : (1 << 30);
        }
        float pmat[4][4];
        #pragma unroll
        for (int kg = 0; kg < 4; kg++) {
            #pragma unroll
            for (int j = 0; j < 4; j++) {
                float s = sacc[kg][j] * rs;
                pmat[kg][j] = (selm[kg] <= qw + lg * 4 + j) ? s : -1e9f;
            }
        }
        float scj[4];
        #pragma unroll
        for (int j = 0; j < 4; j++) {
            float tm = fmaxf(fmaxf(pmat[0][j], pmat[1][j]), fmaxf(pmat[2][j], pmat[3][j]));
            #pragma unroll
            for (int m = 1; m < 16; m <<= 1) tm = fmaxf(tm, __shfl_xor(tm, m));
            float mnew = fmaxf(mrow[j], tm);
            scj[j] = __expf(mrow[j] - mnew);
            mrow[j] = mnew;
            float ps = 0.f;
            #pragma unroll
            for (int kg = 0; kg < 4; kg++) {
                float p = __expf(pmat[kg][j] - mnew);
                pmat[kg][j] = p;
                ps += p;
            }
            #pragma unroll
            for (int m = 1; m < 16; m <<= 1) ps += __shfl_xor(ps, m);
            lrow[j] = lrow[j] * scj[j] + ps;
        }
        #pragma unroll
        for (int kg = 0; kg < 4; kg++) {
            uint2 u;
            u.x = pack2(pmat[kg][0], pmat[kg][1]);
            u.y = pack2(pmat[kg][2], pmat[kg][3]);
            *(uint2*)&Pt[w][(kg * 16 + l15) * 16 + lg * 4] = u;
        }
        {
            float t0 = __shfl(scj[0], bsrc), t1 = __shfl(scj[1], bsrc);
            float t2 = __shfl(scj[2], bsrc), t3 = __shfl(scj[3], bsrc);
            float scq = (jj == 0) ? t0 : (jj == 1) ? t1 : (jj == 2) ? t2 : t3;
            #pragma unroll
            for (int dg = 0; dg < 8; dg++) {
                oacc[dg][0] *= scq; oacc[dg][1] *= scq;
                oacc[dg][2] *= scq; oacc[dg][3] *= scq;
            }
        }
        #pragma unroll
        for (int ks = 0; ks < 2; ks++) {
            bf16x8 pf;
            #pragma unroll
            for (int e = 0; e < 8; e++)
                pf[e] = (short)Pt[w][(ks * 32 + lg * 8 + e) * 16 + l15];
            #pragma unroll
            for (int dg = 0; dg < 8; dg++) {
                int d = dg * 16 + l15;
                int sw = (d ^ (d >> 3)) & 7;
                bf16x8 vf = *(const bf16x8*)&Vt[d * 32 + (((ks * 4 + lg) ^ sw) << 2)];
                oacc[dg] = __builtin_amdgcn_mfma_f32_16x16x32_bf16(vf, pf, oacc[dg], 0, 0, 0);
            }
        }
    }
    float u0 = __shfl(lrow[0], bsrc), u1 = __shfl(lrow[1], bsrc);
    float u2 = __shfl(lrow[2], bsrc), u3 = __shfl(lrow[3], bsrc);
    float lq = (jj == 0) ? u0 : (jj == 1) ? u1 : (jj == 2) ? u2 : u3;
    float li = 1.0f / lq;
    const long obase = ((long)((b * S_ + qw + l15) * H_ + h)) * HD_ + lg * 4;
    #pragma unroll
    for (int dg = 0; dg < 8; dg++) {
        #pragma unroll
        for (int jp = 0; jp < 2; jp++) {
            unsigned o = pack2(oacc[dg][jp * 2] * li, oacc[dg][jp * 2 + 1] * li);
            *(unsigned*)&aob[obase + dg * 16 + jp * 2] = o;
        }
    }
}

// ---------- bf16 MFMA GEMM 128^2 (m97 + T1), for QKV (z=3) and O-proj ----------
// EP 0: store bf16 to Cz;  EP 1: xout = acc + resid (f32)
template<int EP>
__global__ __launch_bounds__(256)
void gemm_k(const bf16* __restrict__ A,
            const bf16* __restrict__ Bt0, const bf16* __restrict__ Bt1, const bf16* __restrict__ Bt2,
            bf16* __restrict__ C0, bf16* __restrict__ C1, bf16* __restrict__ C2,
            const float* __restrict__ resid, float* __restrict__ xout,
            int N, int K) {
    __shared__ bf16 As[128 * 32];
    __shared__ bf16 Bs[128 * 32];
    const int tid = threadIdx.x;
    const int w = tid >> 6, lane = tid & 63;

    // T1 bijective XCD swizzle (m204)
    const int gx = gridDim.x;
    const int nwg = gx * gridDim.y;
    const int orig = blockIdx.y * gx + blockIdx.x;
    const int qc = nwg >> 3, rc = nwg & 7;
    const int xcd = orig & 7, loc = orig >> 3;
    const int wg = (xcd < rc ? xcd * (qc + 1) : rc * (qc + 1) + (xcd - rc) * qc) + loc;
    const int m0 = (wg % gx) * 128, n0 = (wg / gx) * 128;

    const bf16* Bt = (blockIdx.z == 0) ? Bt0 : ((blockIdx.z == 1) ? Bt1 : Bt2);
    bf16* Cb       = (blockIdx.z == 0) ? C0  : ((blockIdx.z == 1) ? C1  : C2);

    const int srow = lane >> 2;
    const int scol = (lane & 3) * 8;
    const long gA = (long)(m0 + w * 32 + srow) * K + scol;
    const long gB = (long)(n0 + w * 32 + srow) * K + scol;

    const int wr = w >> 1, wc = w & 1;
    const int fm = lane & 15, kg = lane >> 4;

    f32x4 acc[4][4] = {};

    for (int kt = 0; kt < K; kt += 32) {
        __syncthreads();
        #pragma unroll
        for (int i = 0; i < 2; i++) {
            load_lds16(A  + gA + (long)(16 * i) * K + kt, &As[(w * 32 + 16 * i) * 32]);
            load_lds16(Bt + gB + (long)(16 * i) * K + kt, &Bs[(w * 32 + 16 * i) * 32]);
        }
        __syncthreads();
        bf16x8 af[4], bfr[4];
        #pragma unroll
        for (int mi = 0; mi < 4; mi++)
            af[mi] = *(const bf16x8*)&As[(wr * 64 + mi * 16 + fm) * 32 + kg * 8];
        #pragma unroll
        for (int ni = 0; ni < 4; ni++)
            bfr[ni] = *(const bf16x8*)&Bs[(wc * 64 + ni * 16 + fm) * 32 + kg * 8];
        #pragma unroll
        for (int mi = 0; mi < 4; mi++)
            #pragma unroll
            for (int ni = 0; ni < 4; ni++)
                acc[mi][ni] = __builtin_amdgcn_mfma_f32_16x16x32_bf16(af[mi], bfr[ni], acc[mi][ni], 0, 0, 0);
    }
    #pragma unroll
    for (int mi = 0; mi < 4; mi++) {
        #pragma unroll
        for (int j = 0; j < 4; j++) {
            const int m = m0 + wr * 64 + mi * 16 + kg * 4 + j;
            #pragma unroll
            for (int ni = 0; ni < 4; ni++) {
                const int n = n0 + wc * 64 + ni * 16 + fm;
                const long off = (long)m * N + n;
                float v = acc[mi][ni][j];
                if (EP == 0) Cb[off] = __float2bfloat16(v);
                else         xout[off] = v + resid[off];
            }
        }
    }
}

// ---------- 256^2 2-phase double-buffered GEMM (8 waves, BK=64, T1+T5) ----------
// C = A[M][lda-rows] @ Bt[N][ldb]^T over kz columns starting at kBase.
// EP 0: z selects {Bt0->C0, Bt1->C1} (fused Wu+Wg), kBase=0
// EP 1: split-K: kBase = z*kz, atomicAdd into psum
template<int EP>
__global__ __launch_bounds__(512, 2)
void gemm256(const bf16* __restrict__ A, int lda,
             const bf16* __restrict__ Bt0, const bf16* __restrict__ Bt1, int ldb,
             int N, int kz,
             bf16* __restrict__ C0, bf16* __restrict__ C1,
             float* __restrict__ psum) {
    __shared__ bf16 As[2][256 * 64];   // 32KB x2
    __shared__ bf16 Bs[2][256 * 64];   // 32KB x2  (total 128KB)
    const int tid = threadIdx.x;
    const int w = tid >> 6, lane = tid & 63;
    const int z = blockIdx.z;

    // T1 bijective XCD swizzle (per z-plane; z-stride multiple of 8)
    const int gx = gridDim.x;
    const int nwg = gx * gridDim.y;
    const int orig = blockIdx.y * gx + blockIdx.x;
    const int qc = nwg >> 3, rc = nwg & 7;
    const int xcd = orig & 7, loc = orig >> 3;
    const int wg = (xcd < rc ? xcd * (qc + 1) : rc * (qc + 1) + (xcd - rc) * qc) + loc;
    const int m0 = (wg % gx) * 256, n0 = (wg / gx) * 256;

    const bf16* Bt = (EP == 0) ? (z ? Bt1 : Bt0) : Bt0;
    const int kBase = (EP == 1) ? z * kz : 0;

    const int wr = w >> 2, wc = w & 3;          // 2x4 wave grid; wave tile 128x64
    const int fm = lane & 15, kg = lane >> 4;
    const int wchunk = tid & ~63;               // w*64

    f32x4 acc[8][4] = {};

    auto stage = [&](int buf, int kt) {
        #pragma unroll
        for (int i = 0; i < 4; i++) {
            int c = i * 512 + tid;               // 16B chunk id; row=c>>3, col8=c&7
            int row = c >> 3, col = (c & 7) * 8;
            load_lds16(A  + (long)(m0 + row) * lda + kBase + kt + col,
                       &As[buf][(i * 512 + wchunk) * 8]);
            load_lds16(Bt + (long)(n0 + row) * ldb + kBase + kt + col,
                       &Bs[buf][(i * 512 + wchunk) * 8]);
        }
    };

    const int nt = kz >> 6;
    stage(0, 0);
    __syncthreads();                             // drains vmcnt
    for (int t = 0; t < nt; t++) {
        const int cur = t & 1;
        if (t + 1 < nt) stage(cur ^ 1, (t + 1) << 6);   // prefetch stays in flight over MFMA
        #pragma unroll
        for (int kk = 0; kk < 2; kk++) {
            bf16x8 af[8], bfr[4];
            #pragma unroll
            for (int mi = 0; mi < 8; mi++)
                af[mi] = *(const bf16x8*)&As[cur][(wr * 128 + mi * 16 + fm) * 64 + kk * 32 + kg * 8];
            #pragma unroll
            for (int ni = 0; ni < 4; ni++)
                bfr[ni] = *(const bf16x8*)&Bs[cur][(wc * 64 + ni * 16 + fm) * 64 + kk * 32 + kg * 8];
            __builtin_amdgcn_s_setprio(1);
            #pragma unroll
            for (int mi = 0; mi < 8; mi++)
                #pragma unroll
                for (int ni = 0; ni < 4; ni++)
                    acc[mi][ni] = __builtin_amdgcn_mfma_f32_16x16x32_bf16(af[mi], bfr[ni], acc[mi][ni], 0, 0, 0);
            __builtin_amdgcn_s_setprio(0);
        }
        __syncthreads();                         // one drain+barrier per K-tile (2-phase)
    }
    #pragma unroll
    for (int mi = 0; mi < 8; mi++) {
        #pragma unroll
        for (int j = 0; j < 4; j++) {
            const int m = m0 + wr * 128 + mi * 16 + kg * 4 + j;
            #pragma unroll
            for (int ni = 0; ni < 4; ni++) {
                const int n = n0 + wc * 64 + ni * 16 + fm;
                const long off = (long)m * N + n;
                float v = acc[mi][ni][j];
                if (EP == 0) (z ? C1 : C0)[off] = __float2bfloat16(v);
                else         unsafeAtomicAdd(&psum[off], v);
            }
        }
    }
}

// ---------- swiglu: u = silu(g) * u ----------
__global__ __launch_bounds__(256)
void swiglu_k(const bf16* __restrict__ g, bf16* __restrict__ u) {
    const long i = ((long)blockIdx.x * 256 + threadIdx.x) * 8;
    bf16x8 gv = *(const bf16x8*)&g[i];
    bf16x8 uv = *(const bf16x8*)&u[i];
    uint4 o;
    unsigned* op = (unsigned*)&o;
    #pragma unroll
    for (int p = 0; p < 4; p++) {
        float g0 = bf2f(gv[p * 2]),     u0 = bf2f(uv[p * 2]);
        float g1 = bf2f(gv[p * 2 + 1]), u1 = bf2f(uv[p * 2 + 1]);
        op[p] = pack2(u0 * g0 / (1.f + __expf(-g0)), u1 * g1 / (1.f + __expf(-g1)));
    }
    *(uint4*)&u[i] = o;
}

// ---------- zero psum ----------
__global__ __launch_bounds__(256)
void zero_k(float4* __restrict__ p) {
    p[(long)blockIdx.x * 256 + threadIdx.x] = make_float4(0.f, 0.f, 0.f, 0.f);
}

// ---------- split-K reduce + residual + MoR routing epilogue ----------
__global__ __launch_bounds__(256)
void reduce_ep3(const float* __restrict__ psum, const float* __restrict__ resid,
                const int* __restrict__ top, const float* __restrict__ wsel,
                float* __restrict__ finalp, float* __restrict__ curp, int rec) {
    const long i = ((long)blockIdx.x * 256 + threadIdx.x) * 4;
    const int m = (int)(i >> 11);   // / D_
    float4 ps = *(const float4*)&psum[i];
    float4 rs = *(const float4*)&resid[i];
    float4 o = make_float4(ps.x + rs.x, ps.y + rs.y, ps.z + rs.z, ps.w + rs.w);
    const int ti = top[m];
    if (ti == rec) {
        const float wv = wsel[m];
        *(float4*)&finalp[i] = make_float4(o.x * wv, o.y * wv, o.z * wv, o.w * wv);
    }
    if (ti >= rec) *(float4*)&curp[i] = o;
}

// ---------- host ----------
extern "C" void kernel_launch(void* const* d_in, const int* in_sizes, int n_in,
                              void* d_out, int out_size, void* d_ws, size_t ws_size,
                              hipStream_t stream) {
    const float* x    = (const float*)d_in[0];
    const float* cosb = (const float*)d_in[1];
    const float* sinb = (const float*)d_in[2];
    const float* wrt  = (const float*)d_in[3];
    const float* ln1  = (const float*)d_in[4];
    const float* ln2  = (const float*)d_in[5];
    const float* Wq   = (const float*)d_in[6];
    const float* Wk   = (const float*)d_in[7];
    const float* Wv   = (const float*)d_in[8];
    const float* Wo   = (const float*)d_in[9];
    const float* Wg   = (const float*)d_in[10];
    const float* Wu   = (const float*)d_in[11];
    const float* Wd   = (const float*)d_in[12];

    char* p = (char*)d_ws;
    auto take = [&](size_t bytes) -> char* {
        char* r = p; p += (bytes + 255) & ~(size_t)255; return r;
    };
    bf16* WqT = (bf16*)take((size_t)D_ * D_ * 2);
    bf16* WkT = (bf16*)take((size_t)D_ * D_ * 2);
    bf16* WvT = (bf16*)take((size_t)D_ * D_ * 2);
    bf16* WoT = (bf16*)take((size_t)D_ * D_ * 2);
    bf16* WgT = (bf16*)take((size_t)D_ * FF_ * 2);
    bf16* WuT = (bf16*)take((size_t)D_ * FF_ * 2);
    bf16* WdT = (bf16*)take((size_t)D_ * FF_ * 2);
    float* cur  = (float*)take((size_t)T_ * D_ * 4);
    float* xnew = (float*)take((size_t)T_ * D_ * 4);
    bf16*  hb   = (bf16*)take((size_t)T_ * D_ * 2);
    bf16*  qb   = (bf16*)take((size_t)T_ * D_ * 2);   // qb..aob: contiguous 32MB,
    bf16*  kbuf = (bf16*)take((size_t)T_ * D_ * 2);   // reused as gb after attn/O-proj
    bf16*  vbuf = (bf16*)take((size_t)T_ * D_ * 2);
    bf16*  aob  = (bf16*)take((size_t)T_ * D_ * 2);
    bf16*  ub   = (bf16*)take((size_t)T_ * FF_ * 2);
    float* psum = (float*)take((size_t)T_ * D_ * 4);
    int*   top  = (int*)take((size_t)T_ * 4);
    float* wsel = (float*)take((size_t)T_ * 4);
    bf16*  gb   = qb;   // alias: g-buffer (32MB) over dead qb/kbuf/vbuf/aob
    (void)ws_size; (void)in_sizes; (void)n_in; (void)out_size;

    transpose_cast<<<dim3(D_ / 32, D_ / 32), 256, 0, stream>>>(Wq, WqT, D_, D_);
    transpose_cast<<<dim3(D_ / 32, D_ / 32), 256, 0, stream>>>(Wk, WkT, D_, D_);
    transpose_cast<<<dim3(D_ / 32, D_ / 32), 256, 0, stream>>>(Wv, WvT, D_, D_);
    transpose_cast<<<dim3(D_ / 32, D_ / 32), 256, 0, stream>>>(Wo, WoT, D_, D_);
    transpose_cast<<<dim3(FF_ / 32, D_ / 32), 256, 0, stream>>>(Wg, WgT, D_, FF_);
    transpose_cast<<<dim3(FF_ / 32, D_ / 32), 256, 0, stream>>>(Wu, WuT, D_, FF_);
    transpose_cast<<<dim3(D_ / 32, FF_ / 32), 256, 0, stream>>>(Wd, WdT, FF_, D_);

    router_k<<<T_ / 4, 256, 0, stream>>>(x, wrt, top, wsel);

    const float* cur_in = x;
    for (int rec = 0; rec < R_; rec++) {
        rmsnorm_k<<<T_, 256, 0, stream>>>(cur_in, ln1, hb);
        // fused QKV (128^2, 768 blocks = 3/CU)
        gemm_k<0><<<dim3(T_ / 128, D_ / 128, 3), 256, 0, stream>>>(
            hb, WqT, WkT, WvT, qb, kbuf, vbuf, nullptr, nullptr, D_, D_);
        rope_k<<<(T_ * H_ * 64) / 256, 256, 0, stream>>>(qb, kbuf, cosb, sinb);
        attn_k<<<dim3(S_ / 64, H_, B_), 256, 0, stream>>>(qb, kbuf, vbuf, top, rec, aob);
        // O proj + residual -> xnew (128^2)
        gemm_k<1><<<dim3(T_ / 128, D_ / 128, 1), 256, 0, stream>>>(
            aob, WoT, nullptr, nullptr, nullptr, nullptr, nullptr, cur_in, xnew, D_, D_);
        rmsnorm_k<<<T_, 256, 0, stream>>>(xnew, ln2, hb);
        // fused Wu + Wg (256^2 2-phase, z=2): ub = h2@Wu, gb = h2@Wg
        gemm256<0><<<dim3(T_ / 256, FF_ / 256, 2), 512, 0, stream>>>(
            hb, D_, WuT, WgT, D_, FF_, D_, ub, gb, nullptr);
        // ub = silu(gb) * ub
        swiglu_k<<<(T_ * FF_) / (256 * 8), 256, 0, stream>>>(gb, ub);
        // down proj: split-K=4 into psum (256^2 2-phase), then reduce+routing
        zero_k<<<(T_ * D_) / (256 * 4), 256, 0, stream>>>((float4*)psum);
        gemm256<1><<<dim3(T_ / 256, D_ / 256, 4), 512, 0, stream>>>(
            ub, FF_, WdT, nullptr, FF_, D_, D_, nullptr, nullptr, psum);
        reduce_ep3<<<(T_ * D_) / (256 * 4), 256, 0, stream>>>(
            psum, xnew, top, wsel, (float*)d_out, cur, rec);
        cur_in = cur;
    }
}

// Round 7
// 1838.931 us; speedup vs baseline: 1.7370x; 1.0651x over previous
//
#include <hip/hip_runtime.h>
#include <hip/hip_bf16.h>

// Problem constants (MoR Llama decoder layer)
#define B_  2
#define S_  1024
#define D_  2048
#define H_  16
#define HD_ 128
#define FF_ 8192
#define R_  3
#define T_  (B_*S_)

typedef __attribute__((ext_vector_type(8))) short bf16x8;   // 8 x bf16 (4 VGPR) MFMA frag
typedef __attribute__((ext_vector_type(4))) float f32x4;    // MFMA accumulator
using bf16 = __hip_bfloat16;

// ---------- helpers ----------
__device__ __forceinline__ float bf2f(short s) {
    return __uint_as_float(((unsigned)(unsigned short)s) << 16);
}
__device__ __forceinline__ unsigned f2bf_bits(float f) {
    bf16 h = __float2bfloat16(f);
    unsigned short u; __builtin_memcpy(&u, &h, 2);
    return (unsigned)u;
}
__device__ __forceinline__ unsigned pack2(float a, float b) {
    return f2bf_bits(a) | (f2bf_bits(b) << 16);
}
__device__ __forceinline__ float wsum(float v) {
    #pragma unroll
    for (int m = 32; m; m >>= 1) v += __shfl_xor(v, m);
    return v;
}
__device__ __forceinline__ void load_lds16(const void* g, void* l) {
    // async global->LDS, 16B per lane; LDS dest is wave-uniform base + lane*16
    __builtin_amdgcn_global_load_lds((const __attribute__((address_space(1))) void*)g,
                                     (__attribute__((address_space(3))) void*)l, 16, 0, 0);
}

// ---------- weight transpose+cast: W[K][N] f32 -> Wt[N][K] bf16 ----------
__global__ __launch_bounds__(256)
void transpose_cast(const float* __restrict__ W, bf16* __restrict__ Wt, int K, int N) {
    __shared__ float tile[32][33];
    const int n0 = blockIdx.x * 32, k0 = blockIdx.y * 32;
    const int c = threadIdx.x & 31, r8 = threadIdx.x >> 5;
    #pragma unroll
    for (int i = 0; i < 4; i++) {
        int r = r8 + i * 8;
        tile[r][c] = W[(long)(k0 + r) * N + n0 + c];
    }
    __syncthreads();
    #pragma unroll
    for (int i = 0; i < 4; i++) {
        int r = r8 + i * 8;
        Wt[(long)(n0 + r) * K + k0 + c] = __float2bfloat16(tile[c][r]);
    }
}

// ---------- router ----------
__global__ __launch_bounds__(256)
void router_k(const float* __restrict__ X, const float* __restrict__ Wr,
              int* __restrict__ top, float* __restrict__ wsel) {
    const int t = blockIdx.x * 4 + (threadIdx.x >> 6);
    const int lane = threadIdx.x & 63;
    const float* x = X + (long)t * D_;
    float a0 = 0.f, a1 = 0.f, a2 = 0.f;
    for (int j = lane; j < D_; j += 64) {
        float xv = x[j];
        a0 += xv * Wr[j * 3 + 0];
        a1 += xv * Wr[j * 3 + 1];
        a2 += xv * Wr[j * 3 + 2];
    }
    a0 = wsum(a0); a1 = wsum(a1); a2 = wsum(a2);
    if (lane == 0) {
        int arg = 0; float bm = a0;
        if (a1 > bm) { bm = a1; arg = 1; }
        if (a2 > bm) { bm = a2; arg = 2; }
        float s = expf(a0 - bm) + expf(a1 - bm) + expf(a2 - bm);
        top[t]  = arg;
        wsel[t] = 1.0f / s;   // softmax value at argmax (TEMP=ALPHA=1)
    }
}

// ---------- RMSNorm f32 -> bf16 ----------
__global__ __launch_bounds__(256)
void rmsnorm_k(const float* __restrict__ X, const float* __restrict__ G, bf16* __restrict__ Hb) {
    const int t = blockIdx.x, tid = threadIdx.x;
    const float4* xr = (const float4*)(X + (long)t * D_);
    float4 v0 = xr[tid], v1 = xr[tid + 256];
    float ss = v0.x*v0.x + v0.y*v0.y + v0.z*v0.z + v0.w*v0.w
             + v1.x*v1.x + v1.y*v1.y + v1.z*v1.z + v1.w*v1.w;
    ss = wsum(ss);
    __shared__ float red[4];
    if ((tid & 63) == 0) red[tid >> 6] = ss;
    __syncthreads();
    const float r = rsqrtf((red[0] + red[1] + red[2] + red[3]) * (1.0f / D_) + 1e-6f);
    const float4* gr = (const float4*)G;
    float4 g0 = gr[tid], g1 = gr[tid + 256];
    uint2* ob = (uint2*)(Hb + (long)t * D_);
    uint2 o;
    o.x = pack2(v0.x * r * g0.x, v0.y * r * g0.y);
    o.y = pack2(v0.z * r * g0.z, v0.w * r * g0.w);
    ob[tid] = o;
    o.x = pack2(v1.x * r * g1.x, v1.y * r * g1.y);
    o.y = pack2(v1.z * r * g1.z, v1.w * r * g1.w);
    ob[tid + 256] = o;
}

// ---------- RoPE in-place on q,k ----------
__global__ __launch_bounds__(256)
void rope_k(bf16* __restrict__ q, bf16* __restrict__ k,
            const float* __restrict__ cosb, const float* __restrict__ sinb) {
    const int idx = blockIdx.x * 256 + threadIdx.x;   // T*H*64 threads
    const int d = idx & 63;
    const int h = (idx >> 6) & (H_ - 1);
    const int t = idx >> 10;
    const int s = t & (S_ - 1);
    const long base = (long)t * D_ + h * HD_;
    const float c1 = cosb[s * HD_ + d],      s1 = sinb[s * HD_ + d];
    const float c2 = cosb[s * HD_ + d + 64], s2 = sinb[s * HD_ + d + 64];
    float q1 = __bfloat162float(q[base + d]), q2 = __bfloat162float(q[base + d + 64]);
    q[base + d]      = __float2bfloat16(q1 * c1 - q2 * s1);
    q[base + d + 64] = __float2bfloat16(q2 * c2 + q1 * s2);
    float k1 = __bfloat162float(k[base + d]), k2 = __bfloat162float(k[base + d + 64]);
    k[base + d]      = __float2bfloat16(k1 * c1 - k2 * s1);
    k[base + d + 64] = __float2bfloat16(k2 * c2 + k1 * s2);
}

// ---------- MFMA flash attention (unchanged, verified rounds 5-6) ----------
__global__ __launch_bounds__(256)
void attn_k(const bf16* __restrict__ qb, const bf16* __restrict__ kb, const bf16* __restrict__ vb,
            const int* __restrict__ top, int rec, bf16* __restrict__ aob) {
    __shared__ bf16 Ks[64 * 128];        // row=key, 16B-chunk swizzle: chunk^=(row&7)
    __shared__ unsigned Vt[128 * 32];    // Vt[d][keypair]; chunk^=((d^(d>>3))&7)
    __shared__ unsigned short Pt[4][64 * 16];  // per-wave P^T[key][q] bf16 bits
    const int tid = threadIdx.x, w = tid >> 6, lane = tid & 63;
    const int l15 = lane & 15, lg = lane >> 4;
    const int q0 = blockIdx.x * 64;
    const int h = blockIdx.y, b = blockIdx.z;
    const int qw = q0 + w * 16;

    bf16x8 Qf[4];
    {
        const bf16* qptr = qb + ((long)((b * S_ + qw + l15) * H_ + h)) * HD_ + lg * 8;
        #pragma unroll
        for (int ds = 0; ds < 4; ds++) Qf[ds] = *(const bf16x8*)(qptr + ds * 32);
    }

    f32x4 oacc[8] = {};
    float mrow[4] = {-1e30f, -1e30f, -1e30f, -1e30f};
    float lrow[4] = {0.f, 0.f, 0.f, 0.f};
    const float rs = 0.088388347648318447f;   // 1/sqrt(128)
    const int bsrc = (l15 >> 2) << 4;
    const int jj = l15 & 3;

    const int nch = blockIdx.x + 1;
    for (int kc = 0; kc < nch; kc++) {
        __syncthreads();
        #pragma unroll
        for (int i = 0; i < 4; i++) {
            int r = w * 16 + i * 4 + lg;
            int key = kc * 64 + r;
            const bf16* src = kb + ((long)((b * S_ + key) * H_ + h)) * HD_ + ((l15 ^ (r & 7)) * 8);
            load_lds16(src, &Ks[(w * 16 + i * 4) * 128]);
        }
        #pragma unroll
        for (int i = 0; i < 2; i++) {
            int j = i * 256 + tid;
            int c = j & 15, r2 = (j >> 4) & 31;
            long gv = ((long)((b * S_ + kc * 64 + 2 * r2) * H_ + h)) * HD_ + c * 8;
            uint4 va = *(const uint4*)&vb[gv];
            uint4 vbn = *(const uint4*)&vb[gv + D_];
            const unsigned short* pa = (const unsigned short*)&va;
            const unsigned short* pb = (const unsigned short*)&vbn;
            #pragma unroll
            for (int e = 0; e < 8; e++) {
                int d = c * 8 + e;
                int sw = (d ^ (d >> 3)) & 7;
                Vt[d * 32 + (((r2 >> 2) ^ sw) << 2) + (r2 & 3)] =
                    (unsigned)pa[e] | ((unsigned)pb[e] << 16);
            }
        }
        __syncthreads();

        f32x4 sacc[4] = {};
        #pragma unroll
        for (int kg = 0; kg < 4; kg++) {
            const int row = kg * 16 + l15;
            #pragma unroll
            for (int ds = 0; ds < 4; ds++) {
                bf16x8 kf = *(const bf16x8*)&Ks[row * 128 + (((ds * 4 + lg) ^ (row & 7)) * 8)];
                sacc[kg] = __builtin_amdgcn_mfma_f32_16x16x32_bf16(Qf[ds], kf, sacc[kg], 0, 0, 0);
            }
        }

        int selm[4];
        #pragma unroll
        for (int kg = 0; kg < 4; kg++) {
            int key = kc * 64 + kg * 16 + l15;
            selm[kg] = (top[b * S_ + key] >= rec) ? (key) : (1 << 30);
        }
        float pmat[4][4];
        #pragma unroll
        for (int kg = 0; kg < 4; kg++) {
            #pragma unroll
            for (int j = 0; j < 4; j++) {
                float s = sacc[kg][j] * rs;
                pmat[kg][j] = (selm[kg] <= qw + lg * 4 + j) ? s : -1e9f;
            }
        }
        float scj[4];
        #pragma unroll
        for (int j = 0; j < 4; j++) {
            float tm = fmaxf(fmaxf(pmat[0][j], pmat[1][j]), fmaxf(pmat[2][j], pmat[3][j]));
            #pragma unroll
            for (int m = 1; m < 16; m <<= 1) tm = fmaxf(tm, __shfl_xor(tm, m));
            float mnew = fmaxf(mrow[j], tm);
            scj[j] = __expf(mrow[j] - mnew);
            mrow[j] = mnew;
            float ps = 0.f;
            #pragma unroll
            for (int kg = 0; kg < 4; kg++) {
                float p = __expf(pmat[kg][j] - mnew);
                pmat[kg][j] = p;
                ps += p;
            }
            #pragma unroll
            for (int m = 1; m < 16; m <<= 1) ps += __shfl_xor(ps, m);
            lrow[j] = lrow[j] * scj[j] + ps;
        }
        #pragma unroll
        for (int kg = 0; kg < 4; kg++) {
            uint2 u;
            u.x = pack2(pmat[kg][0], pmat[kg][1]);
            u.y = pack2(pmat[kg][2], pmat[kg][3]);
            *(uint2*)&Pt[w][(kg * 16 + l15) * 16 + lg * 4] = u;
        }
        {
            float t0 = __shfl(scj[0], bsrc), t1 = __shfl(scj[1], bsrc);
            float t2 = __shfl(scj[2], bsrc), t3 = __shfl(scj[3], bsrc);
            float scq = (jj == 0) ? t0 : (jj == 1) ? t1 : (jj == 2) ? t2 : t3;
            #pragma unroll
            for (int dg = 0; dg < 8; dg++) {
                oacc[dg][0] *= scq; oacc[dg][1] *= scq;
                oacc[dg][2] *= scq; oacc[dg][3] *= scq;
            }
        }
        #pragma unroll
        for (int ks = 0; ks < 2; ks++) {
            bf16x8 pf;
            #pragma unroll
            for (int e = 0; e < 8; e++)
                pf[e] = (short)Pt[w][(ks * 32 + lg * 8 + e) * 16 + l15];
            #pragma unroll
            for (int dg = 0; dg < 8; dg++) {
                int d = dg * 16 + l15;
                int sw = (d ^ (d >> 3)) & 7;
                bf16x8 vf = *(const bf16x8*)&Vt[d * 32 + (((ks * 4 + lg) ^ sw) << 2)];
                oacc[dg] = __builtin_amdgcn_mfma_f32_16x16x32_bf16(vf, pf, oacc[dg], 0, 0, 0);
            }
        }
    }
    float u0 = __shfl(lrow[0], bsrc), u1 = __shfl(lrow[1], bsrc);
    float u2 = __shfl(lrow[2], bsrc), u3 = __shfl(lrow[3], bsrc);
    float lq = (jj == 0) ? u0 : (jj == 1) ? u1 : (jj == 2) ? u2 : u3;
    float li = 1.0f / lq;
    const long obase = ((long)((b * S_ + qw + l15) * H_ + h)) * HD_ + lg * 4;
    #pragma unroll
    for (int dg = 0; dg < 8; dg++) {
        #pragma unroll
        for (int jp = 0; jp < 2; jp++) {
            unsigned o = pack2(oacc[dg][jp * 2] * li, oacc[dg][jp * 2 + 1] * li);
            *(unsigned*)&aob[obase + dg * 16 + jp * 2] = o;
        }
    }
}

// ---------- bf16 MFMA GEMM 128^2 (m97 + T1), for QKV (z=3) and O-proj ----------
template<int EP>
__global__ __launch_bounds__(256)
void gemm_k(const bf16* __restrict__ A,
            const bf16* __restrict__ Bt0, const bf16* __restrict__ Bt1, const bf16* __restrict__ Bt2,
            bf16* __restrict__ C0, bf16* __restrict__ C1, bf16* __restrict__ C2,
            const float* __restrict__ resid, float* __restrict__ xout,
            int N, int K) {
    __shared__ bf16 As[128 * 32];
    __shared__ bf16 Bs[128 * 32];
    const int tid = threadIdx.x;
    const int w = tid >> 6, lane = tid & 63;

    // T1 bijective XCD swizzle (m204)
    const int gx = gridDim.x;
    const int nwg = gx * gridDim.y;
    const int orig = blockIdx.y * gx + blockIdx.x;
    const int qc = nwg >> 3, rc = nwg & 7;
    const int xcd = orig & 7, loc = orig >> 3;
    const int wg = (xcd < rc ? xcd * (qc + 1) : rc * (qc + 1) + (xcd - rc) * qc) + loc;
    const int m0 = (wg % gx) * 128, n0 = (wg / gx) * 128;

    const bf16* Bt = (blockIdx.z == 0) ? Bt0 : ((blockIdx.z == 1) ? Bt1 : Bt2);
    bf16* Cb       = (blockIdx.z == 0) ? C0  : ((blockIdx.z == 1) ? C1  : C2);

    const int srow = lane >> 2;
    const int scol = (lane & 3) * 8;
    const long gA = (long)(m0 + w * 32 + srow) * K + scol;
    const long gB = (long)(n0 + w * 32 + srow) * K + scol;

    const int wr = w >> 1, wc = w & 1;
    const int fm = lane & 15, kg = lane >> 4;

    f32x4 acc[4][4] = {};

    for (int kt = 0; kt < K; kt += 32) {
        __syncthreads();
        #pragma unroll
        for (int i = 0; i < 2; i++) {
            load_lds16(A  + gA + (long)(16 * i) * K + kt, &As[(w * 32 + 16 * i) * 32]);
            load_lds16(Bt + gB + (long)(16 * i) * K + kt, &Bs[(w * 32 + 16 * i) * 32]);
        }
        __syncthreads();
        bf16x8 af[4], bfr[4];
        #pragma unroll
        for (int mi = 0; mi < 4; mi++)
            af[mi] = *(const bf16x8*)&As[(wr * 64 + mi * 16 + fm) * 32 + kg * 8];
        #pragma unroll
        for (int ni = 0; ni < 4; ni++)
            bfr[ni] = *(const bf16x8*)&Bs[(wc * 64 + ni * 16 + fm) * 32 + kg * 8];
        #pragma unroll
        for (int mi = 0; mi < 4; mi++)
            #pragma unroll
            for (int ni = 0; ni < 4; ni++)
                acc[mi][ni] = __builtin_amdgcn_mfma_f32_16x16x32_bf16(af[mi], bfr[ni], acc[mi][ni], 0, 0, 0);
    }
    #pragma unroll
    for (int mi = 0; mi < 4; mi++) {
        #pragma unroll
        for (int j = 0; j < 4; j++) {
            const int m = m0 + wr * 64 + mi * 16 + kg * 4 + j;
            #pragma unroll
            for (int ni = 0; ni < 4; ni++) {
                const int n = n0 + wc * 64 + ni * 16 + fm;
                const long off = (long)m * N + n;
                float v = acc[mi][ni][j];
                if (EP == 0) Cb[off] = __float2bfloat16(v);
                else         xout[off] = v + resid[off];
            }
        }
    }
}

// ---------- 256^2 8-phase GEMM (T2 swizzle + T3/T4 counted vmcnt + T5 setprio) ----------
// m201-derived. LDS: [buf][khalf] 16KB regions; rows paired into 128B lines of 8
// 16B-chunks, chunk XOR-swizzled by (line&7). Staged via global_load_lds with
// inverse-swizzled GLOBAL source (rule #21), LDS dest linear. 4 phases per K-tile:
// {alpha: 8 A-frags + 2 B-frags, 16 MFMA (ni 0,1) | beta: 2 B-frags, 16 MFMA (ni 2,3)}.
// One half-tile (A or B, one K-half: 2 global_load_lds) staged per phase, offset 5
// => steady-state vmcnt(6) before each K-half's first read-phase; drains 6->4->0.
// EP 0: z selects {Bt0->C0, Bt1->C1} (fused Wu+Wg), kBase=0
// EP 1: split-K: kBase = z*kz, atomicAdd into psum
template<int EP>
__global__ __launch_bounds__(512, 2)
void gemm256(const bf16* __restrict__ A, int lda,
             const bf16* __restrict__ Bt0, const bf16* __restrict__ Bt1, int ldb,
             int N, int kz,
             bf16* __restrict__ C0, bf16* __restrict__ C1,
             float* __restrict__ psum) {
    __shared__ bf16 As[32768];   // 64KB: [buf][kh] 16KB regions
    __shared__ bf16 Bs[32768];   // 64KB
    const int tid = threadIdx.x;
    const int w = tid >> 6, lane = tid & 63;
    const int z = blockIdx.z;

    // T1 bijective XCD swizzle (per z-plane; z-stride multiple of 8)
    const int gx = gridDim.x;
    const int nwg = gx * gridDim.y;
    const int orig = blockIdx.y * gx + blockIdx.x;
    const int qc = nwg >> 3, rc = nwg & 7;
    const int xcd = orig & 7, loc = orig >> 3;
    const int wg = (xcd < rc ? xcd * (qc + 1) : rc * (qc + 1) + (xcd - rc) * qc) + loc;
    const int m0 = (wg % gx) * 256, n0 = (wg / gx) * 256;

    const bf16* Bt = (EP == 0) ? (z ? Bt1 : Bt0) : Bt0;
    const int kBase = (EP == 1) ? z * kz : 0;

    const int wr = w >> 2, wc = w & 3;          // 2x4 wave grid; wave tile 128x64
    const int fm = lane & 15, kg = lane >> 4;
    const int nt = kz >> 6;

    f32x4 acc[8][4] = {};

    // stage half-tile h: h = 4t + 2*khalf + (0:A,1:B); target region [t&1][khalf]
    auto stage_half = [&](int h) {
        if (h >= 4 * nt) return;
        const int th = h >> 2, khh = (h >> 1) & 1, isB = h & 1, bufh = th & 1;
        bf16* dst = (isB ? Bs : As) + (bufh * 2 + khh) * 8192;
        const bf16* srcm = isB ? Bt : A;
        const long ldx = isB ? (long)ldb : (long)lda;
        const int rb = isB ? n0 : m0;
        const long colb = (long)kBase + th * 64 + khh * 32;
        #pragma unroll
        for (int j = 0; j < 2; ++j) {
            const int L = j * 64 + (w << 3) + (lane >> 3);     // 128B line (2 rows)
            const int cl = (lane & 7) ^ (L & 7);               // inverse-swizzled chunk
            const bf16* g = srcm + (long)(rb + 2 * L + (cl >> 2)) * ldx + colb + (cl & 3) * 8;
            load_lds16(g, dst + (j * 64 + (w << 3)) * 64);     // wave-uniform linear dest
        }
    };

    // prologue: 5 half-tiles issued; wait until h0,h1 (tile0, khalf0 A+B) landed
    stage_half(0); stage_half(1); stage_half(2); stage_half(3); stage_half(4);
    asm volatile("s_waitcnt vmcnt(6)" ::: "memory");
    __builtin_amdgcn_s_barrier();

    for (int g0 = 0; g0 < 4 * nt; g0 += 2) {    // one K-half (2 phases) per iteration
        const int t = g0 >> 2, kh = (g0 >> 1) & 1, buf = t & 1;
        const bf16* ra  = As + (buf * 2 + kh) * 8192;
        const bf16* rbb = Bs + (buf * 2 + kh) * 8192;
        // ---- phase alpha: read 8 A-frags + B-frags(ni 0,1); stage; 16 MFMA
        bf16x8 af[8], b01[2];
        #pragma unroll
        for (int mi = 0; mi < 8; ++mi) {
            const int row = wr * 128 + mi * 16 + fm;
            const int L = row >> 1;
            const int cp = ((row & 1) * 4 + kg) ^ (L & 7);
            af[mi] = *(const bf16x8*)(ra + L * 64 + cp * 8);
        }
        #pragma unroll
        for (int ni = 0; ni < 2; ++ni) {
            const int row = wc * 64 + ni * 16 + fm;
            const int L = row >> 1;
            const int cp = ((row & 1) * 4 + kg) ^ (L & 7);
            b01[ni] = *(const bf16x8*)(rbb + L * 64 + cp * 8);
        }
        stage_half(g0 + 5);
        __builtin_amdgcn_s_barrier();
        asm volatile("s_waitcnt lgkmcnt(0)" ::: "memory");
        __builtin_amdgcn_sched_barrier(0);
        __builtin_amdgcn_s_setprio(1);
        #pragma unroll
        for (int mi = 0; mi < 8; ++mi) {
            acc[mi][0] = __builtin_amdgcn_mfma_f32_16x16x32_bf16(af[mi], b01[0], acc[mi][0], 0, 0, 0);
            acc[mi][1] = __builtin_amdgcn_mfma_f32_16x16x32_bf16(af[mi], b01[1], acc[mi][1], 0, 0, 0);
        }
        __builtin_amdgcn_s_setprio(0);
        __builtin_amdgcn_s_barrier();
        // ---- phase beta: read B-frags(ni 2,3); stage; 16 MFMA (A-frags reused)
        bf16x8 b23[2];
        #pragma unroll
        for (int ni = 0; ni < 2; ++ni) {
            const int row = wc * 64 + (ni + 2) * 16 + fm;
            const int L = row >> 1;
            const int cp = ((row & 1) * 4 + kg) ^ (L & 7);
            b23[ni] = *(const bf16x8*)(rbb + L * 64 + cp * 8);
        }
        stage_half(g0 + 6);
        __builtin_amdgcn_s_barrier();
        asm volatile("s_waitcnt lgkmcnt(0)" ::: "memory");
        __builtin_amdgcn_sched_barrier(0);
        __builtin_amdgcn_s_setprio(1);
        #pragma unroll
        for (int mi = 0; mi < 8; ++mi) {
            acc[mi][2] = __builtin_amdgcn_mfma_f32_16x16x32_bf16(af[mi], b23[0], acc[mi][2], 0, 0, 0);
            acc[mi][3] = __builtin_amdgcn_mfma_f32_16x16x32_bf16(af[mi], b23[1], acc[mi][3], 0, 0, 0);
        }
        __builtin_amdgcn_s_setprio(0);
        // ---- trailing checkpoint guarding next K-half's reads (counted, never syncthreads)
        const int remp = 4 * nt - g0;
        if (remp >= 8)      asm volatile("s_waitcnt vmcnt(6)" ::: "memory");
        else if (remp == 6) asm volatile("s_waitcnt vmcnt(4)" ::: "memory");
        else if (remp == 4) asm volatile("s_waitcnt vmcnt(0)" ::: "memory");
        __builtin_amdgcn_s_barrier();
    }

    #pragma unroll
    for (int mi = 0; mi < 8; mi++) {
        #pragma unroll
        for (int j = 0; j < 4; j++) {
            const int m = m0 + wr * 128 + mi * 16 + kg * 4 + j;
            #pragma unroll
            for (int ni = 0; ni < 4; ni++) {
                const int n = n0 + wc * 64 + ni * 16 + fm;
                const long off = (long)m * N + n;
                float v = acc[mi][ni][j];
                if (EP == 0) (z ? C1 : C0)[off] = __float2bfloat16(v);
                else         unsafeAtomicAdd(&psum[off], v);
            }
        }
    }
}

// ---------- swiglu: u = silu(g) * u ----------
__global__ __launch_bounds__(256)
void swiglu_k(const bf16* __restrict__ g, bf16* __restrict__ u) {
    const long i = ((long)blockIdx.x * 256 + threadIdx.x) * 8;
    bf16x8 gv = *(const bf16x8*)&g[i];
    bf16x8 uv = *(const bf16x8*)&u[i];
    uint4 o;
    unsigned* op = (unsigned*)&o;
    #pragma unroll
    for (int p = 0; p < 4; p++) {
        float g0 = bf2f(gv[p * 2]),     u0 = bf2f(uv[p * 2]);
        float g1 = bf2f(gv[p * 2 + 1]), u1 = bf2f(uv[p * 2 + 1]);
        op[p] = pack2(u0 * g0 / (1.f + __expf(-g0)), u1 * g1 / (1.f + __expf(-g1)));
    }
    *(uint4*)&u[i] = o;
}

// ---------- zero psum ----------
__global__ __launch_bounds__(256)
void zero_k(float4* __restrict__ p) {
    p[(long)blockIdx.x * 256 + threadIdx.x] = make_float4(0.f, 0.f, 0.f, 0.f);
}

// ---------- split-K reduce + residual + MoR routing epilogue ----------
__global__ __launch_bounds__(256)
void reduce_ep3(const float* __restrict__ psum, const float* __restrict__ resid,
                const int* __restrict__ top, const float* __restrict__ wsel,
                float* __restrict__ finalp, float* __restrict__ curp, int rec) {
    const long i = ((long)blockIdx.x * 256 + threadIdx.x) * 4;
    const int m = (int)(i >> 11);   // / D_
    float4 ps = *(const float4*)&psum[i];
    float4 rs = *(const float4*)&resid[i];
    float4 o = make_float4(ps.x + rs.x, ps.y + rs.y, ps.z + rs.z, ps.w + rs.w);
    const int ti = top[m];
    if (ti == rec) {
        const float wv = wsel[m];
        *(float4*)&finalp[i] = make_float4(o.x * wv, o.y * wv, o.z * wv, o.w * wv);
    }
    if (ti >= rec) *(float4*)&curp[i] = o;
}

// ---------- host ----------
extern "C" void kernel_launch(void* const* d_in, const int* in_sizes, int n_in,
                              void* d_out, int out_size, void* d_ws, size_t ws_size,
                              hipStream_t stream) {
    const float* x    = (const float*)d_in[0];
    const float* cosb = (const float*)d_in[1];
    const float* sinb = (const float*)d_in[2];
    const float* wrt  = (const float*)d_in[3];
    const float* ln1  = (const float*)d_in[4];
    const float* ln2  = (const float*)d_in[5];
    const float* Wq   = (const float*)d_in[6];
    const float* Wk   = (const float*)d_in[7];
    const float* Wv   = (const float*)d_in[8];
    const float* Wo   = (const float*)d_in[9];
    const float* Wg   = (const float*)d_in[10];
    const float* Wu   = (const float*)d_in[11];
    const float* Wd   = (const float*)d_in[12];

    char* p = (char*)d_ws;
    auto take = [&](size_t bytes) -> char* {
        char* r = p; p += (bytes + 255) & ~(size_t)255; return r;
    };
    bf16* WqT = (bf16*)take((size_t)D_ * D_ * 2);
    bf16* WkT = (bf16*)take((size_t)D_ * D_ * 2);
    bf16* WvT = (bf16*)take((size_t)D_ * D_ * 2);
    bf16* WoT = (bf16*)take((size_t)D_ * D_ * 2);
    bf16* WgT = (bf16*)take((size_t)D_ * FF_ * 2);
    bf16* WuT = (bf16*)take((size_t)D_ * FF_ * 2);
    bf16* WdT = (bf16*)take((size_t)D_ * FF_ * 2);
    float* cur  = (float*)take((size_t)T_ * D_ * 4);
    float* xnew = (float*)take((size_t)T_ * D_ * 4);
    bf16*  hb   = (bf16*)take((size_t)T_ * D_ * 2);
    bf16*  qb   = (bf16*)take((size_t)T_ * D_ * 2);   // qb..aob: contiguous 32MB,
    bf16*  kbuf = (bf16*)take((size_t)T_ * D_ * 2);   // reused as gb after attn/O-proj
    bf16*  vbuf = (bf16*)take((size_t)T_ * D_ * 2);
    bf16*  aob  = (bf16*)take((size_t)T_ * D_ * 2);
    bf16*  ub   = (bf16*)take((size_t)T_ * FF_ * 2);
    float* psum = (float*)take((size_t)T_ * D_ * 4);
    int*   top  = (int*)take((size_t)T_ * 4);
    float* wsel = (float*)take((size_t)T_ * 4);
    bf16*  gb   = qb;   // alias: g-buffer (32MB) over dead qb/kbuf/vbuf/aob
    (void)ws_size; (void)in_sizes; (void)n_in; (void)out_size;

    transpose_cast<<<dim3(D_ / 32, D_ / 32), 256, 0, stream>>>(Wq, WqT, D_, D_);
    transpose_cast<<<dim3(D_ / 32, D_ / 32), 256, 0, stream>>>(Wk, WkT, D_, D_);
    transpose_cast<<<dim3(D_ / 32, D_ / 32), 256, 0, stream>>>(Wv, WvT, D_, D_);
    transpose_cast<<<dim3(D_ / 32, D_ / 32), 256, 0, stream>>>(Wo, WoT, D_, D_);
    transpose_cast<<<dim3(FF_ / 32, D_ / 32), 256, 0, stream>>>(Wg, WgT, D_, FF_);
    transpose_cast<<<dim3(FF_ / 32, D_ / 32), 256, 0, stream>>>(Wu, WuT, D_, FF_);
    transpose_cast<<<dim3(D_ / 32, FF_ / 32), 256, 0, stream>>>(Wd, WdT, FF_, D_);

    router_k<<<T_ / 4, 256, 0, stream>>>(x, wrt, top, wsel);

    const float* cur_in = x;
    for (int rec = 0; rec < R_; rec++) {
        rmsnorm_k<<<T_, 256, 0, stream>>>(cur_in, ln1, hb);
        // fused QKV (128^2, 768 blocks = 3/CU)
        gemm_k<0><<<dim3(T_ / 128, D_ / 128, 3), 256, 0, stream>>>(
            hb, WqT, WkT, WvT, qb, kbuf, vbuf, nullptr, nullptr, D_, D_);
        rope_k<<<(T_ * H_ * 64) / 256, 256, 0, stream>>>(qb, kbuf, cosb, sinb);
        attn_k<<<dim3(S_ / 64, H_, B_), 256, 0, stream>>>(qb, kbuf, vbuf, top, rec, aob);
        // O proj + residual -> xnew (128^2)
        gemm_k<1><<<dim3(T_ / 128, D_ / 128, 1), 256, 0, stream>>>(
            aob, WoT, nullptr, nullptr, nullptr, nullptr, nullptr, cur_in, xnew, D_, D_);
        rmsnorm_k<<<T_, 256, 0, stream>>>(xnew, ln2, hb);
        // fused Wu + Wg (256^2 8-phase, z=2): ub = h2@Wu, gb = h2@Wg
        gemm256<0><<<dim3(T_ / 256, FF_ / 256, 2), 512, 0, stream>>>(
            hb, D_, WuT, WgT, D_, FF_, D_, ub, gb, nullptr);
        // ub = silu(gb) * ub
        swiglu_k<<<(T_ * FF_) / (256 * 8), 256, 0, stream>>>(gb, ub);
        // down proj: split-K=4 into psum (256^2 8-phase), then reduce+routing
        zero_k<<<(T_ * D_) / (256 * 4), 256, 0, stream>>>((float4*)psum);
        gemm256<1><<<dim3(T_ / 256, D_ / 256, 4), 512, 0, stream>>>(
            ub, FF_, WdT, nullptr, FF_, D_, D_, nullptr, nullptr, psum);
        reduce_ep3<<<(T_ * D_) / (256 * 4), 256, 0, stream>>>(
            psum, xnew, top, wsel, (float*)d_out, cur, rec);
        cur_in = cur;
    }
}